// Round 1
// baseline (194.907 us; speedup 1.0000x reference)
//
#include <hip/hip_runtime.h>

// Fast Tucker-Taylor forward, fp32 decomposition.
// Shapes: X(4096,1024) -> Y(4096,1024). RANK=32, ORDER=3.
//
// Pipeline:
//   Wcat(192,1024) = concat(I0,I1,I2)           [concat_kernel]
//   Ocat(1024,96)  = [O0@G0 | O1 | O2]          [concat_kernel]
//   Z(4096,192)    = X @ Wcat^T                 [gemm_bt<0>]
//   T(4096,0..31)  = kron(z11,z10) @ G1^T       [kron_t1, split-K=4 + atomics]
//   T(4096,32..63) = (kron(z21,z20) @ G2m^T) contracted with z22  [kron_t2]
//   Y = const + [Z(:,0:32) | T] @ Ocat^T        [gemm_bt<1>]

typedef float f4 __attribute__((ext_vector_type(4)));

// ws layout (float offsets)
#define Z_OFF   0            // 4096*192 = 786432
#define T_OFF   786432       // 4096*64  = 262144
#define W_OFF   1048576      // 192*1024 = 196608
#define OC_OFF  1245184      // 1024*96  = 98304
// total 1343488 floats = 5.4 MB

__global__ __launch_bounds__(256) void concat_kernel(
    const float* __restrict__ I0, const float* __restrict__ I1, const float* __restrict__ I2,
    const float* __restrict__ O0, const float* __restrict__ O1, const float* __restrict__ O2,
    const float* __restrict__ G0, float* __restrict__ Wcat, float* __restrict__ Ocat)
{
    int gid = blockIdx.x * 256 + threadIdx.x;
    if (gid < 196608) {
        float v;
        if (gid < 32768)      v = I0[gid];
        else if (gid < 98304) v = I1[gid - 32768];
        else                  v = I2[gid - 98304];
        Wcat[gid] = v;
    } else {
        int idx = gid - 196608;
        if (idx < 98304) {
            int o = idx / 96, j = idx % 96;
            float v;
            if (j < 32) {
                v = 0.f;
                #pragma unroll
                for (int q = 0; q < 32; ++q) v += O0[o*32 + q] * G0[q*32 + j];
            } else if (j < 64) v = O1[o*32 + (j - 32)];
            else               v = O2[o*32 + (j - 64)];
            Ocat[idx] = v;
        }
    }
}

// Generic C = A @ B^T (+bias), BM=BN=64, BK=32, 256 thr, 4x4 microtile.
// MODE 0: A is a plain row-major (M,K) matrix.
// MODE 1: K=96 composite A: k in [0,32) from Zsrc cols 0..31 (lda 192),
//         k in [32,96) from Tsrc cols 0..63 (lda 64).
template<int MODE, bool BIAS>
__global__ __launch_bounds__(256) void gemm_bt(
    const float* __restrict__ A, int lda,
    const float* __restrict__ Zsrc, const float* __restrict__ Tsrc,
    const float* __restrict__ Bm, int ldb,
    const float* __restrict__ bias,
    float* __restrict__ C, int ldc, int K)
{
    __shared__ float As[32][68];
    __shared__ float Bs[32][68];
    const int t  = threadIdx.x;
    const int n0 = blockIdx.x * 64, m0 = blockIdx.y * 64;
    const int ty = t >> 4, tx = t & 15;
    const int lm = t >> 2, kq = (t & 3) * 8;
    f4 acc[4] = {};   // acc[i][j] : rows ty*4+i, cols tx*4+j

    for (int k0 = 0; k0 < K; k0 += 32) {
        const float* ap;
        if (MODE == 0) ap = A + (size_t)(m0 + lm) * lda + k0 + kq;
        else           ap = (k0 == 0) ? (Zsrc + (size_t)(m0 + lm) * 192 + kq)
                                      : (Tsrc + (size_t)(m0 + lm) * 64 + (k0 - 32) + kq);
        f4 a0 = *(const f4*)ap, a1 = *(const f4*)(ap + 4);
        const float* bp = Bm + (size_t)(n0 + lm) * ldb + k0 + kq;
        f4 b0 = *(const f4*)bp, b1 = *(const f4*)(bp + 4);
        __syncthreads();
        #pragma unroll
        for (int j = 0; j < 4; ++j) {
            As[kq + j][lm]     = a0[j];
            As[kq + 4 + j][lm] = a1[j];
            Bs[kq + j][lm]     = b0[j];
            Bs[kq + 4 + j][lm] = b1[j];
        }
        __syncthreads();
        #pragma unroll
        for (int kk = 0; kk < 32; ++kk) {
            f4 av = *(const f4*)&As[kk][ty * 4];
            f4 bv = *(const f4*)&Bs[kk][tx * 4];
            #pragma unroll
            for (int i = 0; i < 4; ++i) acc[i] += av[i] * bv;
        }
    }
    #pragma unroll
    for (int i = 0; i < 4; ++i) {
        f4 out = acc[i];
        if (BIAS) out += *(const f4*)&bias[n0 + tx * 4];
        *(f4*)&C[(size_t)(m0 + ty * 4 + i) * ldc + n0 + tx * 4] = out;
    }
}

// t1 = kron(z11,z10) @ G1^T, split-K=4, atomicAdd into T cols 0..31.
// Z cols 32..63 = z10 (I1 slice0), 64..95 = z11 (I1 slice1).
__global__ __launch_bounds__(256) void kron_t1(
    const float* __restrict__ Z, const float* __restrict__ G1, float* __restrict__ T)
{
    __shared__ float Zs[64][68];
    __shared__ float As[32][68];
    __shared__ float Bs[32][36];
    const int t  = threadIdx.x;
    const int ks = blockIdx.x;            // K-split 0..3
    const int m0 = blockIdx.y * 64;
    {
        int row = t >> 2, cq = (t & 3) * 16;
        const float* zp = Z + (size_t)(m0 + row) * 192 + 32 + cq;
        #pragma unroll
        for (int q = 0; q < 4; ++q) *(f4*)&Zs[row][cq + 4*q] = *(const f4*)(zp + 4*q);
    }
    __syncthreads();
    const int ty = t >> 4, tx = t & 15;
    const int sn = t >> 3, kq4 = (t & 7) * 4;
    const int sm = t >> 2, kq8 = (t & 3) * 8;
    float acc[4][2] = {};
    for (int k0 = ks * 256; k0 < ks * 256 + 256; k0 += 32) {
        const int r1 = k0 >> 5;                 // constant within the K-tile
        f4 g   = *(const f4*)&G1[(size_t)sn * 1024 + k0 + kq4];
        f4 z0a = *(const f4*)&Zs[sm][kq8];
        f4 z0b = *(const f4*)&Zs[sm][kq8 + 4];
        float z1v = Zs[sm][32 + r1];
        __syncthreads();
        #pragma unroll
        for (int j = 0; j < 4; ++j) {
            Bs[kq4 + j][sn]     = g[j];
            As[kq8 + j][sm]     = z1v * z0a[j];
            As[kq8 + 4 + j][sm] = z1v * z0b[j];
        }
        __syncthreads();
        #pragma unroll
        for (int kk = 0; kk < 32; ++kk) {
            f4 av = *(const f4*)&As[kk][ty * 4];
            float b0 = Bs[kk][tx * 2], b1 = Bs[kk][tx * 2 + 1];
            #pragma unroll
            for (int i = 0; i < 4; ++i) { acc[i][0] += av[i] * b0; acc[i][1] += av[i] * b1; }
        }
    }
    #pragma unroll
    for (int i = 0; i < 4; ++i) {
        atomicAdd(&T[(size_t)(m0 + ty * 4 + i) * 64 + tx * 2],     acc[i][0]);
        atomicAdd(&T[(size_t)(m0 + ty * 4 + i) * 64 + tx * 2 + 1], acc[i][1]);
    }
}

// t2: M = kron(z21,z20) @ G2m^T (G2 viewed as (1024,1024) row-major),
// epilogue contracts 32-col groups with z22, writes T cols 32..63.
// BM=BN=128, BK=32. Z cols 96..127=z20, 128..159=z21, 160..191=z22.
__global__ __launch_bounds__(256) void kron_t2(
    const float* __restrict__ Z, const float* __restrict__ G2, float* __restrict__ T)
{
    __shared__ float smem[17152];          // 68.6 KB, reused for epilogue M-tile
    float* Zs = smem;                      // [128][68]
    float* As = smem + 128 * 68;           // [32][132]
    float* Bs = As + 32 * 132;             // [32][132]
    const int t  = threadIdx.x;
    const int n0 = blockIdx.x * 128;
    const int m0 = blockIdx.y * 128;
    {
        int row = t >> 1, cq = (t & 1) * 32;
        const float* zp = Z + (size_t)(m0 + row) * 192 + 96 + cq;
        #pragma unroll
        for (int q = 0; q < 8; ++q) *(f4*)&Zs[row * 68 + cq + 4*q] = *(const f4*)(zp + 4*q);
    }
    __syncthreads();
    const int ty = t >> 4, tx = t & 15;
    const int sm = t >> 1, skh = (t & 1) * 16;
    f4 acc[2][2][4] = {};
    for (int k0 = 0; k0 < 1024; k0 += 32) {
        const int r1 = k0 >> 5;
        const float* gp = G2 + (size_t)(n0 + sm) * 1024 + k0 + skh;
        f4 g0 = *(const f4*)gp, g1 = *(const f4*)(gp + 4),
           g2 = *(const f4*)(gp + 8), g3 = *(const f4*)(gp + 12);
        f4 z0[4];
        #pragma unroll
        for (int q = 0; q < 4; ++q) z0[q] = *(const f4*)&Zs[sm * 68 + skh + 4*q];
        float z1v = Zs[sm * 68 + 32 + r1];
        __syncthreads();
        #pragma unroll
        for (int j = 0; j < 4; ++j) {
            As[(skh + j)  * 132 + sm] = z1v * z0[0][j];
            As[(skh + 4 + j) * 132 + sm] = z1v * z0[1][j];
            As[(skh + 8 + j) * 132 + sm] = z1v * z0[2][j];
            As[(skh + 12 + j)* 132 + sm] = z1v * z0[3][j];
            Bs[(skh + j)  * 132 + sm] = g0[j];
            Bs[(skh + 4 + j) * 132 + sm] = g1[j];
            Bs[(skh + 8 + j) * 132 + sm] = g2[j];
            Bs[(skh + 12 + j)* 132 + sm] = g3[j];
        }
        __syncthreads();
        #pragma unroll
        for (int kk = 0; kk < 32; ++kk) {
            f4 a0 = *(const f4*)&As[kk * 132 + ty * 4];
            f4 a1 = *(const f4*)&As[kk * 132 + 64 + ty * 4];
            f4 b0 = *(const f4*)&Bs[kk * 132 + tx * 4];
            f4 b1 = *(const f4*)&Bs[kk * 132 + 64 + tx * 4];
            #pragma unroll
            for (int i = 0; i < 4; ++i) {
                acc[0][0][i] += a0[i] * b0;
                acc[0][1][i] += a0[i] * b1;
                acc[1][0][i] += a1[i] * b0;
                acc[1][1][i] += a1[i] * b1;
            }
        }
    }
    // epilogue: M-tile -> LDS, contract r2 with z22 (global), write t2
    __syncthreads();
    float* M = smem;                       // [128][132]
    #pragma unroll
    for (int h = 0; h < 2; ++h)
        #pragma unroll
        for (int i = 0; i < 4; ++i) {
            *(f4*)&M[(h*64 + ty*4 + i) * 132 + tx*4]      = acc[h][0][i];
            *(f4*)&M[(h*64 + ty*4 + i) * 132 + 64 + tx*4] = acc[h][1][i];
        }
    __syncthreads();
    #pragma unroll
    for (int s = 0; s < 2; ++s) {
        int task = t + s * 256;
        int row = task >> 2, rl = task & 3;
        const float* z2p = Z + (size_t)(m0 + row) * 192 + 160;
        float sum = 0.f;
        #pragma unroll
        for (int r2 = 0; r2 < 32; ++r2) sum += M[row * 132 + rl * 32 + r2] * z2p[r2];
        T[(size_t)(m0 + row) * 64 + 32 + blockIdx.x * 4 + rl] = sum;
    }
}

extern "C" void kernel_launch(void* const* d_in, const int* in_sizes, int n_in,
                              void* d_out, int out_size, void* d_ws, size_t ws_size,
                              hipStream_t stream) {
    const float* X   = (const float*)d_in[0];
    const float* cst = (const float*)d_in[1];
    const float* O0  = (const float*)d_in[2];
    const float* I0  = (const float*)d_in[3];
    const float* G0  = (const float*)d_in[4];
    const float* O1  = (const float*)d_in[5];
    const float* I1  = (const float*)d_in[6];
    const float* G1  = (const float*)d_in[7];
    const float* O2  = (const float*)d_in[8];
    const float* I2  = (const float*)d_in[9];
    const float* G2  = (const float*)d_in[10];
    float* ws = (float*)d_ws;
    float* Z  = ws + Z_OFF;
    float* T  = ws + T_OFF;
    float* Wc = ws + W_OFF;
    float* Oc = ws + OC_OFF;
    float* Y  = (float*)d_out;

    hipMemsetAsync(T, 0, 4096 * 64 * sizeof(float), stream);
    concat_kernel<<<1152, 256, 0, stream>>>(I0, I1, I2, O0, O1, O2, G0, Wc, Oc);
    gemm_bt<0, false><<<dim3(3, 64), 256, 0, stream>>>(
        X, 1024, nullptr, nullptr, Wc, 1024, nullptr, Z, 192, 1024);
    kron_t1<<<dim3(4, 64), 256, 0, stream>>>(Z, G1, T);
    kron_t2<<<dim3(8, 32), 256, 0, stream>>>(Z, G2, T);
    gemm_bt<1, true><<<dim3(16, 64), 256, 0, stream>>>(
        nullptr, 0, Z, T, Oc, 96, cst, Y, 1024, 96);
}

// Round 2
// 107.222 us; speedup vs baseline: 1.8178x; 1.8178x over previous
//
#include <hip/hip_runtime.h>

// Fast Tucker-Taylor forward. Round 2: kron_t2 -> f16 MFMA.
//
// Pipeline:
//   Wcat(192,1024) = concat(I0,I1,I2)           [concat_kernel]
//   Ocat(1024,96)  = [O0@G0 | O1 | O2]          [concat_kernel]
//   G2h            = f16(G2)                     [cvt_g2]
//   Z(4096,192)    = X @ Wcat^T                 [gemm_bt<0>, fp32]
//   T(4096,0..31)  = kron(z11,z10) @ G1^T       [kron_t1, fp32 split-K + atomics]
//   T(4096,32..63) = (kron(z21,z20) @ G2m^T) . z22   [kron_t2_mfma, f16 MFMA]
//   Y = const + [Z(:,0:32) | T] @ Ocat^T        [gemm_bt<1>, fp32]

typedef float f4 __attribute__((ext_vector_type(4)));
typedef _Float16 h8 __attribute__((ext_vector_type(8)));
typedef _Float16 h4 __attribute__((ext_vector_type(4)));
typedef _Float16 h2 __attribute__((ext_vector_type(2)));

// ws layout (float offsets)
#define Z_OFF   0            // 4096*192 = 786432
#define T_OFF   786432       // 4096*64  = 262144
#define W_OFF   1048576      // 192*1024 = 196608
#define OC_OFF  1245184      // 1024*96  = 98304
#define G2H_OFF 1343488      // 1024*1024 f16 = 262144 float slots
// total 1605632 floats = 6.4 MB

__global__ __launch_bounds__(256) void concat_kernel(
    const float* __restrict__ I0, const float* __restrict__ I1, const float* __restrict__ I2,
    const float* __restrict__ O0, const float* __restrict__ O1, const float* __restrict__ O2,
    const float* __restrict__ G0, float* __restrict__ Wcat, float* __restrict__ Ocat)
{
    int gid = blockIdx.x * 256 + threadIdx.x;
    if (gid < 196608) {
        float v;
        if (gid < 32768)      v = I0[gid];
        else if (gid < 98304) v = I1[gid - 32768];
        else                  v = I2[gid - 98304];
        Wcat[gid] = v;
    } else {
        int idx = gid - 196608;
        if (idx < 98304) {
            int o = idx / 96, j = idx % 96;
            float v;
            if (j < 32) {
                v = 0.f;
                #pragma unroll
                for (int q = 0; q < 32; ++q) v += O0[o*32 + q] * G0[q*32 + j];
            } else if (j < 64) v = O1[o*32 + (j - 32)];
            else               v = O2[o*32 + (j - 64)];
            Ocat[idx] = v;
        }
    }
}

__global__ __launch_bounds__(256) void cvt_g2(
    const float* __restrict__ G2, _Float16* __restrict__ G2h)
{
    int i = (blockIdx.x * 256 + threadIdx.x) * 4;
    f4 v = *(const f4*)(G2 + i);
    h4 o = { (_Float16)v[0], (_Float16)v[1], (_Float16)v[2], (_Float16)v[3] };
    *(h4*)(G2h + i) = o;
}

// Generic C = A @ B^T (+bias), fp32. BM=BN=64, BK=32, 256 thr, 4x4 microtile.
template<int MODE, bool BIAS>
__global__ __launch_bounds__(256) void gemm_bt(
    const float* __restrict__ A, int lda,
    const float* __restrict__ Zsrc, const float* __restrict__ Tsrc,
    const float* __restrict__ Bm, int ldb,
    const float* __restrict__ bias,
    float* __restrict__ C, int ldc, int K)
{
    __shared__ float As[32][68];
    __shared__ float Bs[32][68];
    const int t  = threadIdx.x;
    const int n0 = blockIdx.x * 64, m0 = blockIdx.y * 64;
    const int ty = t >> 4, tx = t & 15;
    const int lm = t >> 2, kq = (t & 3) * 8;
    f4 acc[4] = {};

    for (int k0 = 0; k0 < K; k0 += 32) {
        const float* ap;
        if (MODE == 0) ap = A + (size_t)(m0 + lm) * lda + k0 + kq;
        else           ap = (k0 == 0) ? (Zsrc + (size_t)(m0 + lm) * 192 + kq)
                                      : (Tsrc + (size_t)(m0 + lm) * 64 + (k0 - 32) + kq);
        f4 a0 = *(const f4*)ap, a1 = *(const f4*)(ap + 4);
        const float* bp = Bm + (size_t)(n0 + lm) * ldb + k0 + kq;
        f4 b0 = *(const f4*)bp, b1 = *(const f4*)(bp + 4);
        __syncthreads();
        #pragma unroll
        for (int j = 0; j < 4; ++j) {
            As[kq + j][lm]     = a0[j];
            As[kq + 4 + j][lm] = a1[j];
            Bs[kq + j][lm]     = b0[j];
            Bs[kq + 4 + j][lm] = b1[j];
        }
        __syncthreads();
        #pragma unroll
        for (int kk = 0; kk < 32; ++kk) {
            f4 av = *(const f4*)&As[kk][ty * 4];
            f4 bv = *(const f4*)&Bs[kk][tx * 4];
            #pragma unroll
            for (int i = 0; i < 4; ++i) acc[i] += av[i] * bv;
        }
    }
    #pragma unroll
    for (int i = 0; i < 4; ++i) {
        f4 out = acc[i];
        if (BIAS) out += *(const f4*)&bias[n0 + tx * 4];
        *(f4*)&C[(size_t)(m0 + ty * 4 + i) * ldc + n0 + tx * 4] = out;
    }
}

// t1 = kron(z11,z10) @ G1^T, split-K=4, atomicAdd into T cols 0..31.
__global__ __launch_bounds__(256) void kron_t1(
    const float* __restrict__ Z, const float* __restrict__ G1, float* __restrict__ T)
{
    __shared__ float Zs[64][68];
    __shared__ float As[32][68];
    __shared__ float Bs[32][36];
    const int t  = threadIdx.x;
    const int ks = blockIdx.x;
    const int m0 = blockIdx.y * 64;
    {
        int row = t >> 2, cq = (t & 3) * 16;
        const float* zp = Z + (size_t)(m0 + row) * 192 + 32 + cq;
        #pragma unroll
        for (int q = 0; q < 4; ++q) *(f4*)&Zs[row][cq + 4*q] = *(const f4*)(zp + 4*q);
    }
    __syncthreads();
    const int ty = t >> 4, tx = t & 15;
    const int sn = t >> 3, kq4 = (t & 7) * 4;
    const int sm = t >> 2, kq8 = (t & 3) * 8;
    float acc[4][2] = {};
    for (int k0 = ks * 256; k0 < ks * 256 + 256; k0 += 32) {
        const int r1 = k0 >> 5;
        f4 g   = *(const f4*)&G1[(size_t)sn * 1024 + k0 + kq4];
        f4 z0a = *(const f4*)&Zs[sm][kq8];
        f4 z0b = *(const f4*)&Zs[sm][kq8 + 4];
        float z1v = Zs[sm][32 + r1];
        __syncthreads();
        #pragma unroll
        for (int j = 0; j < 4; ++j) {
            Bs[kq4 + j][sn]     = g[j];
            As[kq8 + j][sm]     = z1v * z0a[j];
            As[kq8 + 4 + j][sm] = z1v * z0b[j];
        }
        __syncthreads();
        #pragma unroll
        for (int kk = 0; kk < 32; ++kk) {
            f4 av = *(const f4*)&As[kk][ty * 4];
            float b0 = Bs[kk][tx * 2], b1 = Bs[kk][tx * 2 + 1];
            #pragma unroll
            for (int i = 0; i < 4; ++i) { acc[i][0] += av[i] * b0; acc[i][1] += av[i] * b1; }
        }
    }
    #pragma unroll
    for (int i = 0; i < 4; ++i) {
        atomicAdd(&T[(size_t)(m0 + ty * 4 + i) * 64 + tx * 2],     acc[i][0]);
        atomicAdd(&T[(size_t)(m0 + ty * 4 + i) * 64 + tx * 2 + 1], acc[i][1]);
    }
}

// t2 via f16 MFMA. M = kron(z21,z20) @ G2m^T, fused r2-contraction epilogue.
// BM=128, BN=64, BK=32 (= one r1 block per K-step). grid (16,32) = 512 blocks.
// 4 waves, each owns 64x32 subtile -> acc[4][2] of 16x16 frags.
// A-frag built in registers: z0-frag preloaded once; per step 1 ds_read (z1
// broadcast pair) + 4 v_pk_mul_f16 per m-tile. B reg-staged to padded LDS,
// double-buffered, one barrier per step.
union AF { h2 q[4]; h8 v; };

__global__ __launch_bounds__(256) void kron_t2_mfma(
    const float* __restrict__ Z, const _Float16* __restrict__ G2h, float* __restrict__ T)
{
    __shared__ __align__(16) unsigned char smem[33792];
    unsigned int* Zs1 = (unsigned int*)smem;            // [128][33] half2-broadcast of z21
    _Float16*    Bs  = (_Float16*)(smem + 16896);       // [2][64][40] padded f16
    float*       Ms  = (float*)smem;                    // [128][66] epilogue reuse

    const int t  = threadIdx.x;
    const int n0 = blockIdx.x * 64;
    const int m0 = blockIdx.y * 128;
    const int wid = t >> 6, lane = t & 63;
    const int wm0 = (wid >> 1) * 64, wn0 = (wid & 1) * 32;
    const int lr = lane & 15, lg = lane >> 4;

    // --- prologue: Zs1 (z21 as broadcast half2 pairs) ---
    {
        int row = t >> 1, c0 = (t & 1) * 16;
        const f4* zp = (const f4*)(Z + (size_t)(m0 + row) * 192 + 128 + c0);
        unsigned int* dst = Zs1 + row * 33 + c0;
        #pragma unroll
        for (int q = 0; q < 4; ++q) {
            f4 v = zp[q];
            #pragma unroll
            for (int j = 0; j < 4; ++j) {
                _Float16 h = (_Float16)v[j];
                unsigned short us = __builtin_bit_cast(unsigned short, h);
                dst[q * 4 + j] = (unsigned int)us * 0x00010001u;
            }
        }
    }
    // --- prologue: z20 fragment in registers (k-slice fixed per lane) ---
    h2 a0h[4][4];
    #pragma unroll
    for (int mt = 0; mt < 4; ++mt) {
        const float* zp = Z + (size_t)(m0 + wm0 + mt*16 + lr) * 192 + 96 + lg * 8;
        f4 v0 = *(const f4*)zp, v1 = *(const f4*)(zp + 4);
        a0h[mt][0] = h2{ (_Float16)v0[0], (_Float16)v0[1] };
        a0h[mt][1] = h2{ (_Float16)v0[2], (_Float16)v0[3] };
        a0h[mt][2] = h2{ (_Float16)v1[0], (_Float16)v1[1] };
        a0h[mt][3] = h2{ (_Float16)v1[2], (_Float16)v1[3] };
    }

    f4 acc[4][2];
    #pragma unroll
    for (int mt = 0; mt < 4; ++mt)
        #pragma unroll
        for (int nt = 0; nt < 2; ++nt) acc[mt][nt] = f4{0.f, 0.f, 0.f, 0.f};

    // --- K loop: 32 steps (one r1 block each), double-buffered B ---
    const int brow = t >> 2, bg = t & 3;
    const f4* gsrc = (const f4*)(G2h + (size_t)(n0 + brow) * 1024 + bg * 8);
    f4 breg = gsrc[0];
    int cur = 0;
    for (int s = 0; s < 32; ++s) {
        f4 bnext;
        if (s + 1 < 32) bnext = gsrc[(s + 1) * 4];
        *(f4*)&Bs[cur * 2560 + brow * 40 + bg * 8] = breg;
        __syncthreads();
        h8 bf0 = *(const h8*)&Bs[cur * 2560 + (wn0 + lr) * 40 + lg * 8];
        h8 bf1 = *(const h8*)&Bs[cur * 2560 + (wn0 + 16 + lr) * 40 + lg * 8];
        #pragma unroll
        for (int mt = 0; mt < 4; ++mt) {
            unsigned int z1u = Zs1[(wm0 + mt*16 + lr) * 33 + s];
            h2 z1h2 = __builtin_bit_cast(h2, z1u);
            AF af;
            af.q[0] = z1h2 * a0h[mt][0];
            af.q[1] = z1h2 * a0h[mt][1];
            af.q[2] = z1h2 * a0h[mt][2];
            af.q[3] = z1h2 * a0h[mt][3];
            acc[mt][0] = __builtin_amdgcn_mfma_f32_16x16x32_f16(af.v, bf0, acc[mt][0], 0, 0, 0);
            acc[mt][1] = __builtin_amdgcn_mfma_f32_16x16x32_f16(af.v, bf1, acc[mt][1], 0, 0, 0);
        }
        breg = bnext;
        cur ^= 1;
    }

    // --- epilogue: M tile -> LDS, contract r2 with fp32 z22 ---
    __syncthreads();
    #pragma unroll
    for (int mt = 0; mt < 4; ++mt)
        #pragma unroll
        for (int nt = 0; nt < 2; ++nt)
            #pragma unroll
            for (int i = 0; i < 4; ++i)
                Ms[(wm0 + mt*16 + lg*4 + i) * 66 + wn0 + nt*16 + lr] = acc[mt][nt][i];
    __syncthreads();
    {
        int row = t >> 1, rl = t & 1;
        const float* z2p = Z + (size_t)(m0 + row) * 192 + 160;
        const float* mrow = Ms + row * 66 + rl * 32;
        float sum = 0.f;
        #pragma unroll
        for (int r2 = 0; r2 < 32; ++r2) sum += mrow[r2] * z2p[r2];
        T[(size_t)(m0 + row) * 64 + 32 + (n0 >> 5) + rl] = sum;
    }
}

extern "C" void kernel_launch(void* const* d_in, const int* in_sizes, int n_in,
                              void* d_out, int out_size, void* d_ws, size_t ws_size,
                              hipStream_t stream) {
    const float* X   = (const float*)d_in[0];
    const float* cst = (const float*)d_in[1];
    const float* O0  = (const float*)d_in[2];
    const float* I0  = (const float*)d_in[3];
    const float* G0  = (const float*)d_in[4];
    const float* O1  = (const float*)d_in[5];
    const float* I1  = (const float*)d_in[6];
    const float* G1  = (const float*)d_in[7];
    const float* O2  = (const float*)d_in[8];
    const float* I2  = (const float*)d_in[9];
    const float* G2  = (const float*)d_in[10];
    float* ws = (float*)d_ws;
    float* Z  = ws + Z_OFF;
    float* T  = ws + T_OFF;
    float* Wc = ws + W_OFF;
    float* Oc = ws + OC_OFF;
    _Float16* G2h = (_Float16*)(ws + G2H_OFF);
    float* Y  = (float*)d_out;

    hipMemsetAsync(T, 0, 4096 * 64 * sizeof(float), stream);
    concat_kernel<<<1152, 256, 0, stream>>>(I0, I1, I2, O0, O1, O2, G0, Wc, Oc);
    cvt_g2<<<1024, 256, 0, stream>>>(G2, G2h);
    gemm_bt<0, false><<<dim3(3, 64), 256, 0, stream>>>(
        X, 1024, nullptr, nullptr, Wc, 1024, nullptr, Z, 192, 1024);
    kron_t1<<<dim3(4, 64), 256, 0, stream>>>(Z, G1, T);
    kron_t2_mfma<<<dim3(16, 32), 256, 0, stream>>>(Z, G2h, T);
    gemm_bt<1, true><<<dim3(16, 64), 256, 0, stream>>>(
        nullptr, 0, Z, T, Oc, 96, cst, Y, 1024, 96);
}

// Round 3
// 64.863 us; speedup vs baseline: 3.0049x; 1.6530x over previous
//
#include <hip/hip_runtime.h>

// Fast Tucker-Taylor forward. Round 3: Z-GEMM and kron_t1 -> f16 MFMA.
//
// Pipeline:
//   Wch(192,1024)f16 + Ocat(1024,96)f32 = concat   [concat_kernel]
//   G2h = f16(G2)                                   [cvt_g2]
//   Z(4096,192)f32 = X @ Wch^T                      [gemm_x_mfma, f16 MFMA]
//   T(:,0..31)  = kron(z11,z10) @ G1^T              [kron_t1_mfma, f16 MFMA]
//   T(:,32..63) = (kron(z21,z20) @ G2m^T) . z22     [kron_t2_mfma, f16 MFMA]
//   Y = const + [Z(:,0:32) | T] @ Ocat^T            [gemm_bt<1>, fp32]

typedef float f4 __attribute__((ext_vector_type(4)));
typedef _Float16 h8 __attribute__((ext_vector_type(8)));
typedef _Float16 h4 __attribute__((ext_vector_type(4)));
typedef _Float16 h2 __attribute__((ext_vector_type(2)));

// ws layout (float offsets)
#define Z_OFF   0            // 4096*192 = 786432
#define T_OFF   786432       // 4096*64  = 262144
#define WH_OFF  1048576      // 192*1024 f16 = 98304 float slots
#define OC_OFF  1146880      // 1024*96  = 98304
#define G2H_OFF 1245184      // 1024*1024 f16 = 524288 float slots
// total 1769472 floats = 7.1 MB

union AF { h2 q[4]; h8 v; };

__global__ __launch_bounds__(256) void concat_kernel(
    const float* __restrict__ I0, const float* __restrict__ I1, const float* __restrict__ I2,
    const float* __restrict__ O0, const float* __restrict__ O1, const float* __restrict__ O2,
    const float* __restrict__ G0, _Float16* __restrict__ Wch, float* __restrict__ Ocat)
{
    int gid = blockIdx.x * 256 + threadIdx.x;
    if (gid < 196608) {
        float v;
        if (gid < 32768)      v = I0[gid];
        else if (gid < 98304) v = I1[gid - 32768];
        else                  v = I2[gid - 98304];
        Wch[gid] = (_Float16)v;
    } else {
        int idx = gid - 196608;
        if (idx < 98304) {
            int o = idx / 96, j = idx % 96;
            float v;
            if (j < 32) {
                v = 0.f;
                #pragma unroll
                for (int q = 0; q < 32; ++q) v += O0[o*32 + q] * G0[q*32 + j];
            } else if (j < 64) v = O1[o*32 + (j - 32)];
            else               v = O2[o*32 + (j - 64)];
            Ocat[idx] = v;
        }
    }
}

__global__ __launch_bounds__(256) void cvt_g2(
    const float* __restrict__ G2, _Float16* __restrict__ G2h)
{
    int i = (blockIdx.x * 256 + threadIdx.x) * 4;
    f4 v = *(const f4*)(G2 + i);
    h4 o = { (_Float16)v[0], (_Float16)v[1], (_Float16)v[2], (_Float16)v[3] };
    *(h4*)(G2h + i) = o;
}

// Z = X @ Wch^T via f16 MFMA, in-kernel fp32->f16 conversion of X.
// BM=BN=64, BK=64, 4 waves (2x2), 192 blocks, chunked XCD swizzle.
__global__ __launch_bounds__(256) void gemm_x_mfma(
    const float* __restrict__ X, const _Float16* __restrict__ Wch,
    float* __restrict__ Z)
{
    __shared__ _Float16 As[64 * 64];   // XOR-swizzled, pitch 64
    __shared__ _Float16 Bs[64 * 64];
    const int t = threadIdx.x;
    const int hw = blockIdx.x;
    const int work = (hw & 7) * 24 + (hw >> 3);     // XCD-chunked (192 = 8*24)
    const int m0 = (work / 3) * 64, n0 = (work % 3) * 64;
    const int wid = t >> 6, lane = t & 63;
    const int wr = wid >> 1, wc = wid & 1;
    const int lr = lane & 15, lg = lane >> 4;
    const int arow = t >> 2, aq = t & 3;

    const float*    xbase = X   + (size_t)(m0 + arow) * 1024 + aq * 16;
    const _Float16* wbase = Wch + (size_t)(n0 + arow) * 1024 + aq * 16;
    const int g0 = aq * 2, g1 = aq * 2 + 1;
    const int sw0 = arow * 64 + ((g0 ^ (arow & 7)) << 3);
    const int sw1 = arow * 64 + ((g1 ^ (arow & 7)) << 3);

    f4 xa[4]; h8 wb[2];
    #pragma unroll
    for (int q = 0; q < 4; ++q) xa[q] = *(const f4*)(xbase + q * 4);
    wb[0] = *(const h8*)wbase;
    wb[1] = *(const h8*)(wbase + 8);

    f4 acc[2][2];
    #pragma unroll
    for (int mt = 0; mt < 2; ++mt)
        #pragma unroll
        for (int nt = 0; nt < 2; ++nt) acc[mt][nt] = f4{0.f,0.f,0.f,0.f};

    for (int s = 0; s < 16; ++s) {
        h8 ha0, ha1;
        #pragma unroll
        for (int j = 0; j < 4; ++j) {
            ha0[j] = (_Float16)xa[0][j]; ha0[4+j] = (_Float16)xa[1][j];
            ha1[j] = (_Float16)xa[2][j]; ha1[4+j] = (_Float16)xa[3][j];
        }
        *(h8*)&As[sw0] = ha0;
        *(h8*)&As[sw1] = ha1;
        *(h8*)&Bs[sw0] = wb[0];
        *(h8*)&Bs[sw1] = wb[1];
        __syncthreads();
        if (s < 15) {
            const float* xp = xbase + (s + 1) * 64;
            #pragma unroll
            for (int q = 0; q < 4; ++q) xa[q] = *(const f4*)(xp + q * 4);
            wb[0] = *(const h8*)(wbase + (s + 1) * 64);
            wb[1] = *(const h8*)(wbase + (s + 1) * 64 + 8);
        }
        #pragma unroll
        for (int ks = 0; ks < 2; ++ks) {
            h8 av[2], bv[2];
            #pragma unroll
            for (int mt = 0; mt < 2; ++mt) {
                int row = wr * 32 + mt * 16 + lr, gg = ks * 4 + lg;
                av[mt] = *(const h8*)&As[row * 64 + ((gg ^ (row & 7)) << 3)];
            }
            #pragma unroll
            for (int nt = 0; nt < 2; ++nt) {
                int row = wc * 32 + nt * 16 + lr, gg = ks * 4 + lg;
                bv[nt] = *(const h8*)&Bs[row * 64 + ((gg ^ (row & 7)) << 3)];
            }
            #pragma unroll
            for (int mt = 0; mt < 2; ++mt)
                #pragma unroll
                for (int nt = 0; nt < 2; ++nt)
                    acc[mt][nt] = __builtin_amdgcn_mfma_f32_16x16x32_f16(av[mt], bv[nt], acc[mt][nt], 0, 0, 0);
        }
        __syncthreads();
    }
    #pragma unroll
    for (int mt = 0; mt < 2; ++mt)
        #pragma unroll
        for (int nt = 0; nt < 2; ++nt)
            #pragma unroll
            for (int i = 0; i < 4; ++i)
                Z[(size_t)(m0 + wr*32 + mt*16 + lg*4 + i) * 192 + n0 + wc*32 + nt*16 + lr] = acc[mt][nt][i];
}

// t1 = kron(z11,z10) @ G1^T via f16 MFMA. BM=128, BN=32, grid 32.
// Whole G1 (f16, pitch 1032) in LDS; no barriers in K-loop; direct store.
__global__ __launch_bounds__(256) void kron_t1_mfma(
    const float* __restrict__ Z, const float* __restrict__ G1, float* __restrict__ T)
{
    __shared__ __align__(16) unsigned char smem[16896 + 66048];
    unsigned int* Zs1 = (unsigned int*)smem;            // [128][33] z11 broadcast
    _Float16* G1s = (_Float16*)(smem + 16896);          // [32][1032]
    const int t = threadIdx.x;
    const int m0 = blockIdx.x * 128;
    const int wid = t >> 6, lane = t & 63;
    const int lr = lane & 15, lg = lane >> 4;

    {   // z11 -> broadcast half2
        int row = t >> 1, c0 = (t & 1) * 16;
        const f4* zp = (const f4*)(Z + (size_t)(m0 + row) * 192 + 64 + c0);
        unsigned int* dst = Zs1 + row * 33 + c0;
        #pragma unroll
        for (int q = 0; q < 4; ++q) {
            f4 v = zp[q];
            #pragma unroll
            for (int j = 0; j < 4; ++j) {
                _Float16 h = (_Float16)v[j];
                unsigned short us = __builtin_bit_cast(unsigned short, h);
                dst[q * 4 + j] = (unsigned int)us * 0x00010001u;
            }
        }
    }
    {   // G1 fp32 -> f16 LDS
        #pragma unroll
        for (int j = 0; j < 32; ++j) {
            int flat = j * 1024 + t * 4;
            f4 v = *(const f4*)(G1 + flat);
            int row = flat >> 10, col = flat & 1023;
            h4 h = { (_Float16)v[0], (_Float16)v[1], (_Float16)v[2], (_Float16)v[3] };
            *(h4*)&G1s[row * 1032 + col] = h;
        }
    }
    // z10 register frags
    h2 a0h[2][4];
    #pragma unroll
    for (int mt = 0; mt < 2; ++mt) {
        const float* zp = Z + (size_t)(m0 + wid*32 + mt*16 + lr) * 192 + 32 + lg * 8;
        f4 v0 = *(const f4*)zp, v1 = *(const f4*)(zp + 4);
        a0h[mt][0] = h2{ (_Float16)v0[0], (_Float16)v0[1] };
        a0h[mt][1] = h2{ (_Float16)v0[2], (_Float16)v0[3] };
        a0h[mt][2] = h2{ (_Float16)v1[0], (_Float16)v1[1] };
        a0h[mt][3] = h2{ (_Float16)v1[2], (_Float16)v1[3] };
    }
    __syncthreads();

    f4 acc[2][2];
    #pragma unroll
    for (int mt = 0; mt < 2; ++mt)
        #pragma unroll
        for (int nt = 0; nt < 2; ++nt) acc[mt][nt] = f4{0.f,0.f,0.f,0.f};

    for (int s = 0; s < 32; ++s) {
        h8 bv[2];
        #pragma unroll
        for (int nt = 0; nt < 2; ++nt)
            bv[nt] = *(const h8*)&G1s[(nt*16 + lr) * 1032 + s * 32 + lg * 8];
        #pragma unroll
        for (int mt = 0; mt < 2; ++mt) {
            unsigned int z1u = Zs1[(wid*32 + mt*16 + lr) * 33 + s];
            h2 z1h2 = __builtin_bit_cast(h2, z1u);
            AF af;
            af.q[0] = z1h2 * a0h[mt][0];
            af.q[1] = z1h2 * a0h[mt][1];
            af.q[2] = z1h2 * a0h[mt][2];
            af.q[3] = z1h2 * a0h[mt][3];
            acc[mt][0] = __builtin_amdgcn_mfma_f32_16x16x32_f16(af.v, bv[0], acc[mt][0], 0, 0, 0);
            acc[mt][1] = __builtin_amdgcn_mfma_f32_16x16x32_f16(af.v, bv[1], acc[mt][1], 0, 0, 0);
        }
    }
    #pragma unroll
    for (int mt = 0; mt < 2; ++mt)
        #pragma unroll
        for (int nt = 0; nt < 2; ++nt)
            #pragma unroll
            for (int i = 0; i < 4; ++i)
                T[(size_t)(m0 + wid*32 + mt*16 + lg*4 + i) * 64 + nt*16 + lr] = acc[mt][nt][i];
}

// t2 via f16 MFMA (unchanged from round 2).
__global__ __launch_bounds__(256) void kron_t2_mfma(
    const float* __restrict__ Z, const _Float16* __restrict__ G2h, float* __restrict__ T)
{
    __shared__ __align__(16) unsigned char smem[33792];
    unsigned int* Zs1 = (unsigned int*)smem;            // [128][33]
    _Float16*    Bs  = (_Float16*)(smem + 16896);       // [2][64][40]
    float*       Ms  = (float*)smem;                    // [128][66] epilogue

    const int t  = threadIdx.x;
    const int n0 = blockIdx.x * 64;
    const int m0 = blockIdx.y * 128;
    const int wid = t >> 6, lane = t & 63;
    const int wm0 = (wid >> 1) * 64, wn0 = (wid & 1) * 32;
    const int lr = lane & 15, lg = lane >> 4;

    {
        int row = t >> 1, c0 = (t & 1) * 16;
        const f4* zp = (const f4*)(Z + (size_t)(m0 + row) * 192 + 128 + c0);
        unsigned int* dst = Zs1 + row * 33 + c0;
        #pragma unroll
        for (int q = 0; q < 4; ++q) {
            f4 v = zp[q];
            #pragma unroll
            for (int j = 0; j < 4; ++j) {
                _Float16 h = (_Float16)v[j];
                unsigned short us = __builtin_bit_cast(unsigned short, h);
                dst[q * 4 + j] = (unsigned int)us * 0x00010001u;
            }
        }
    }
    h2 a0h[4][4];
    #pragma unroll
    for (int mt = 0; mt < 4; ++mt) {
        const float* zp = Z + (size_t)(m0 + wm0 + mt*16 + lr) * 192 + 96 + lg * 8;
        f4 v0 = *(const f4*)zp, v1 = *(const f4*)(zp + 4);
        a0h[mt][0] = h2{ (_Float16)v0[0], (_Float16)v0[1] };
        a0h[mt][1] = h2{ (_Float16)v0[2], (_Float16)v0[3] };
        a0h[mt][2] = h2{ (_Float16)v1[0], (_Float16)v1[1] };
        a0h[mt][3] = h2{ (_Float16)v1[2], (_Float16)v1[3] };
    }

    f4 acc[4][2];
    #pragma unroll
    for (int mt = 0; mt < 4; ++mt)
        #pragma unroll
        for (int nt = 0; nt < 2; ++nt) acc[mt][nt] = f4{0.f, 0.f, 0.f, 0.f};

    const int brow = t >> 2, bg = t & 3;
    const f4* gsrc = (const f4*)(G2h + (size_t)(n0 + brow) * 1024 + bg * 8);
    f4 breg = gsrc[0];
    int cur = 0;
    for (int s = 0; s < 32; ++s) {
        f4 bnext;
        if (s + 1 < 32) bnext = gsrc[(s + 1) * 4];
        *(f4*)&Bs[cur * 2560 + brow * 40 + bg * 8] = breg;
        __syncthreads();
        h8 bf0 = *(const h8*)&Bs[cur * 2560 + (wn0 + lr) * 40 + lg * 8];
        h8 bf1 = *(const h8*)&Bs[cur * 2560 + (wn0 + 16 + lr) * 40 + lg * 8];
        #pragma unroll
        for (int mt = 0; mt < 4; ++mt) {
            unsigned int z1u = Zs1[(wm0 + mt*16 + lr) * 33 + s];
            h2 z1h2 = __builtin_bit_cast(h2, z1u);
            AF af;
            af.q[0] = z1h2 * a0h[mt][0];
            af.q[1] = z1h2 * a0h[mt][1];
            af.q[2] = z1h2 * a0h[mt][2];
            af.q[3] = z1h2 * a0h[mt][3];
            acc[mt][0] = __builtin_amdgcn_mfma_f32_16x16x32_f16(af.v, bf0, acc[mt][0], 0, 0, 0);
            acc[mt][1] = __builtin_amdgcn_mfma_f32_16x16x32_f16(af.v, bf1, acc[mt][1], 0, 0, 0);
        }
        breg = bnext;
        cur ^= 1;
    }

    __syncthreads();
    #pragma unroll
    for (int mt = 0; mt < 4; ++mt)
        #pragma unroll
        for (int nt = 0; nt < 2; ++nt)
            #pragma unroll
            for (int i = 0; i < 4; ++i)
                Ms[(wm0 + mt*16 + lg*4 + i) * 66 + wn0 + nt*16 + lr] = acc[mt][nt][i];
    __syncthreads();
    {
        int row = t >> 1, rl = t & 1;
        const float* z2p = Z + (size_t)(m0 + row) * 192 + 160;
        const float* mrow = Ms + row * 66 + rl * 32;
        float sum = 0.f;
        #pragma unroll
        for (int r2 = 0; r2 < 32; ++r2) sum += mrow[r2] * z2p[r2];
        T[(size_t)(m0 + row) * 64 + 32 + (n0 >> 5) + rl] = sum;
    }
}

// Final GEMM: Y = const + [Z(:,0:32) | T] @ Ocat^T  (fp32, K=96)
template<int MODE, bool BIAS>
__global__ __launch_bounds__(256) void gemm_bt(
    const float* __restrict__ A, int lda,
    const float* __restrict__ Zsrc, const float* __restrict__ Tsrc,
    const float* __restrict__ Bm, int ldb,
    const float* __restrict__ bias,
    float* __restrict__ C, int ldc, int K)
{
    __shared__ float As[32][68];
    __shared__ float Bs[32][68];
    const int t  = threadIdx.x;
    const int n0 = blockIdx.x * 64, m0 = blockIdx.y * 64;
    const int ty = t >> 4, tx = t & 15;
    const int lm = t >> 2, kq = (t & 3) * 8;
    f4 acc[4] = {};

    for (int k0 = 0; k0 < K; k0 += 32) {
        const float* ap;
        if (MODE == 0) ap = A + (size_t)(m0 + lm) * lda + k0 + kq;
        else           ap = (k0 == 0) ? (Zsrc + (size_t)(m0 + lm) * 192 + kq)
                                      : (Tsrc + (size_t)(m0 + lm) * 64 + (k0 - 32) + kq);
        f4 a0 = *(const f4*)ap, a1 = *(const f4*)(ap + 4);
        const float* bp = Bm + (size_t)(n0 + lm) * ldb + k0 + kq;
        f4 b0 = *(const f4*)bp, b1 = *(const f4*)(bp + 4);
        __syncthreads();
        #pragma unroll
        for (int j = 0; j < 4; ++j) {
            As[kq + j][lm]     = a0[j];
            As[kq + 4 + j][lm] = a1[j];
            Bs[kq + j][lm]     = b0[j];
            Bs[kq + 4 + j][lm] = b1[j];
        }
        __syncthreads();
        #pragma unroll
        for (int kk = 0; kk < 32; ++kk) {
            f4 av = *(const f4*)&As[kk][ty * 4];
            f4 bv = *(const f4*)&Bs[kk][tx * 4];
            #pragma unroll
            for (int i = 0; i < 4; ++i) acc[i] += av[i] * bv;
        }
    }
    #pragma unroll
    for (int i = 0; i < 4; ++i) {
        f4 out = acc[i];
        if (BIAS) out += *(const f4*)&bias[n0 + tx * 4];
        *(f4*)&C[(size_t)(m0 + ty * 4 + i) * ldc + n0 + tx * 4] = out;
    }
}

extern "C" void kernel_launch(void* const* d_in, const int* in_sizes, int n_in,
                              void* d_out, int out_size, void* d_ws, size_t ws_size,
                              hipStream_t stream) {
    const float* X   = (const float*)d_in[0];
    const float* cst = (const float*)d_in[1];
    const float* O0  = (const float*)d_in[2];
    const float* I0  = (const float*)d_in[3];
    const float* G0  = (const float*)d_in[4];
    const float* O1  = (const float*)d_in[5];
    const float* I1  = (const float*)d_in[6];
    const float* G1  = (const float*)d_in[7];
    const float* O2  = (const float*)d_in[8];
    const float* I2  = (const float*)d_in[9];
    const float* G2  = (const float*)d_in[10];
    float* ws = (float*)d_ws;
    float* Z  = ws + Z_OFF;
    float* T  = ws + T_OFF;
    _Float16* Wh = (_Float16*)(ws + WH_OFF);
    float* Oc = ws + OC_OFF;
    _Float16* G2h = (_Float16*)(ws + G2H_OFF);
    float* Y  = (float*)d_out;

    concat_kernel<<<1152, 256, 0, stream>>>(I0, I1, I2, O0, O1, O2, G0, Wh, Oc);
    cvt_g2<<<1024, 256, 0, stream>>>(G2, G2h);
    gemm_x_mfma<<<192, 256, 0, stream>>>(X, Wh, Z);
    kron_t1_mfma<<<32, 256, 0, stream>>>(Z, G1, T);
    kron_t2_mfma<<<dim3(16, 32), 256, 0, stream>>>(Z, G2h, T);
    gemm_bt<1, true><<<dim3(16, 64), 256, 0, stream>>>(
        nullptr, 0, Z, T, Oc, 96, cst, Y, 1024, 96);
}

// Round 4
// 55.209 us; speedup vs baseline: 3.5304x; 1.1749x over previous
//
#include <hip/hip_runtime.h>

// Fast Tucker-Taylor forward. Round 4: final GEMM -> f16 MFMA; merged prep.
//
// Pipeline:
//   Wch(192,1024)f16, Och(1024,96)f16, G2h f16 = concat_all  [one kernel]
//   Z(4096,192)f32 = X @ Wch^T                      [gemm_x_mfma]
//   T(:,0..31)  = kron(z11,z10) @ G1^T              [kron_t1_mfma]
//   T(:,32..63) = (kron(z21,z20) @ G2m^T) . z22     [kron_t2_mfma]
//   Y = const + [Z(:,0:32) | T] @ Och^T             [gemm_y_mfma]

typedef float f4 __attribute__((ext_vector_type(4)));
typedef _Float16 h8 __attribute__((ext_vector_type(8)));
typedef _Float16 h4 __attribute__((ext_vector_type(4)));
typedef _Float16 h2 __attribute__((ext_vector_type(2)));

// ws layout (float offsets)
#define Z_OFF   0            // 4096*192 = 786432
#define T_OFF   786432       // 4096*64  = 262144
#define WH_OFF  1048576      // 192*1024 f16 = 98304 float slots
#define OC_OFF  1146880      // 1024*96 f16 = 49152 float slots
#define G2H_OFF 1196032      // 1024*1024 f16 = 524288 float slots
// total 1720320 floats = 6.9 MB

union AF { h2 q[4]; h8 v; };

// blocks 0..1151: Wch + Och; blocks 1152..2175: G2 -> f16
__global__ __launch_bounds__(256) void concat_all(
    const float* __restrict__ I0, const float* __restrict__ I1, const float* __restrict__ I2,
    const float* __restrict__ O0, const float* __restrict__ O1, const float* __restrict__ O2,
    const float* __restrict__ G0, const float* __restrict__ G2,
    _Float16* __restrict__ Wch, _Float16* __restrict__ Och, _Float16* __restrict__ G2h)
{
    if (blockIdx.x >= 1152) {
        int i = ((blockIdx.x - 1152) * 256 + threadIdx.x) * 4;
        f4 v = *(const f4*)(G2 + i);
        h4 o = { (_Float16)v[0], (_Float16)v[1], (_Float16)v[2], (_Float16)v[3] };
        *(h4*)(G2h + i) = o;
        return;
    }
    int gid = blockIdx.x * 256 + threadIdx.x;
    if (gid < 196608) {
        float v;
        if (gid < 32768)      v = I0[gid];
        else if (gid < 98304) v = I1[gid - 32768];
        else                  v = I2[gid - 98304];
        Wch[gid] = (_Float16)v;
    } else {
        int idx = gid - 196608;
        if (idx < 98304) {
            int o = idx / 96, j = idx % 96;
            float v;
            if (j < 32) {
                v = 0.f;
                #pragma unroll
                for (int q = 0; q < 32; ++q) v += O0[o*32 + q] * G0[q*32 + j];
            } else if (j < 64) v = O1[o*32 + (j - 32)];
            else               v = O2[o*32 + (j - 64)];
            Och[idx] = (_Float16)v;
        }
    }
}

// Z = X @ Wch^T via f16 MFMA, in-kernel fp32->f16 conversion of X.
// BM=BN=64, BK=64, 4 waves (2x2), 192 blocks, chunked XCD swizzle.
__global__ __launch_bounds__(256) void gemm_x_mfma(
    const float* __restrict__ X, const _Float16* __restrict__ Wch,
    float* __restrict__ Z)
{
    __shared__ _Float16 As[64 * 64];
    __shared__ _Float16 Bs[64 * 64];
    const int t = threadIdx.x;
    const int hw = blockIdx.x;
    const int work = (hw & 7) * 24 + (hw >> 3);
    const int m0 = (work / 3) * 64, n0 = (work % 3) * 64;
    const int wid = t >> 6, lane = t & 63;
    const int wr = wid >> 1, wc = wid & 1;
    const int lr = lane & 15, lg = lane >> 4;
    const int arow = t >> 2, aq = t & 3;

    const float*    xbase = X   + (size_t)(m0 + arow) * 1024 + aq * 16;
    const _Float16* wbase = Wch + (size_t)(n0 + arow) * 1024 + aq * 16;
    const int g0 = aq * 2, g1 = aq * 2 + 1;
    const int sw0 = arow * 64 + ((g0 ^ (arow & 7)) << 3);
    const int sw1 = arow * 64 + ((g1 ^ (arow & 7)) << 3);

    f4 xa[4]; h8 wb[2];
    #pragma unroll
    for (int q = 0; q < 4; ++q) xa[q] = *(const f4*)(xbase + q * 4);
    wb[0] = *(const h8*)wbase;
    wb[1] = *(const h8*)(wbase + 8);

    f4 acc[2][2];
    #pragma unroll
    for (int mt = 0; mt < 2; ++mt)
        #pragma unroll
        for (int nt = 0; nt < 2; ++nt) acc[mt][nt] = f4{0.f,0.f,0.f,0.f};

    for (int s = 0; s < 16; ++s) {
        h8 ha0, ha1;
        #pragma unroll
        for (int j = 0; j < 4; ++j) {
            ha0[j] = (_Float16)xa[0][j]; ha0[4+j] = (_Float16)xa[1][j];
            ha1[j] = (_Float16)xa[2][j]; ha1[4+j] = (_Float16)xa[3][j];
        }
        *(h8*)&As[sw0] = ha0;
        *(h8*)&As[sw1] = ha1;
        *(h8*)&Bs[sw0] = wb[0];
        *(h8*)&Bs[sw1] = wb[1];
        __syncthreads();
        if (s < 15) {
            const float* xp = xbase + (s + 1) * 64;
            #pragma unroll
            for (int q = 0; q < 4; ++q) xa[q] = *(const f4*)(xp + q * 4);
            wb[0] = *(const h8*)(wbase + (s + 1) * 64);
            wb[1] = *(const h8*)(wbase + (s + 1) * 64 + 8);
        }
        #pragma unroll
        for (int ks = 0; ks < 2; ++ks) {
            h8 av[2], bv[2];
            #pragma unroll
            for (int mt = 0; mt < 2; ++mt) {
                int row = wr * 32 + mt * 16 + lr, gg = ks * 4 + lg;
                av[mt] = *(const h8*)&As[row * 64 + ((gg ^ (row & 7)) << 3)];
            }
            #pragma unroll
            for (int nt = 0; nt < 2; ++nt) {
                int row = wc * 32 + nt * 16 + lr, gg = ks * 4 + lg;
                bv[nt] = *(const h8*)&Bs[row * 64 + ((gg ^ (row & 7)) << 3)];
            }
            #pragma unroll
            for (int mt = 0; mt < 2; ++mt)
                #pragma unroll
                for (int nt = 0; nt < 2; ++nt)
                    acc[mt][nt] = __builtin_amdgcn_mfma_f32_16x16x32_f16(av[mt], bv[nt], acc[mt][nt], 0, 0, 0);
        }
        __syncthreads();
    }
    #pragma unroll
    for (int mt = 0; mt < 2; ++mt)
        #pragma unroll
        for (int nt = 0; nt < 2; ++nt)
            #pragma unroll
            for (int i = 0; i < 4; ++i)
                Z[(size_t)(m0 + wr*32 + mt*16 + lg*4 + i) * 192 + n0 + wc*32 + nt*16 + lr] = acc[mt][nt][i];
}

// t1 = kron(z11,z10) @ G1^T via f16 MFMA. BM=128, BN=32, grid 32.
__global__ __launch_bounds__(256) void kron_t1_mfma(
    const float* __restrict__ Z, const float* __restrict__ G1, float* __restrict__ T)
{
    __shared__ __align__(16) unsigned char smem[16896 + 66048];
    unsigned int* Zs1 = (unsigned int*)smem;
    _Float16* G1s = (_Float16*)(smem + 16896);
    const int t = threadIdx.x;
    const int m0 = blockIdx.x * 128;
    const int wid = t >> 6, lane = t & 63;
    const int lr = lane & 15, lg = lane >> 4;

    {
        int row = t >> 1, c0 = (t & 1) * 16;
        const f4* zp = (const f4*)(Z + (size_t)(m0 + row) * 192 + 64 + c0);
        unsigned int* dst = Zs1 + row * 33 + c0;
        #pragma unroll
        for (int q = 0; q < 4; ++q) {
            f4 v = zp[q];
            #pragma unroll
            for (int j = 0; j < 4; ++j) {
                _Float16 h = (_Float16)v[j];
                unsigned short us = __builtin_bit_cast(unsigned short, h);
                dst[q * 4 + j] = (unsigned int)us * 0x00010001u;
            }
        }
    }
    {
        #pragma unroll
        for (int j = 0; j < 32; ++j) {
            int flat = j * 1024 + t * 4;
            f4 v = *(const f4*)(G1 + flat);
            int row = flat >> 10, col = flat & 1023;
            h4 h = { (_Float16)v[0], (_Float16)v[1], (_Float16)v[2], (_Float16)v[3] };
            *(h4*)&G1s[row * 1032 + col] = h;
        }
    }
    h2 a0h[2][4];
    #pragma unroll
    for (int mt = 0; mt < 2; ++mt) {
        const float* zp = Z + (size_t)(m0 + wid*32 + mt*16 + lr) * 192 + 32 + lg * 8;
        f4 v0 = *(const f4*)zp, v1 = *(const f4*)(zp + 4);
        a0h[mt][0] = h2{ (_Float16)v0[0], (_Float16)v0[1] };
        a0h[mt][1] = h2{ (_Float16)v0[2], (_Float16)v0[3] };
        a0h[mt][2] = h2{ (_Float16)v1[0], (_Float16)v1[1] };
        a0h[mt][3] = h2{ (_Float16)v1[2], (_Float16)v1[3] };
    }
    __syncthreads();

    f4 acc[2][2];
    #pragma unroll
    for (int mt = 0; mt < 2; ++mt)
        #pragma unroll
        for (int nt = 0; nt < 2; ++nt) acc[mt][nt] = f4{0.f,0.f,0.f,0.f};

    for (int s = 0; s < 32; ++s) {
        h8 bv[2];
        #pragma unroll
        for (int nt = 0; nt < 2; ++nt)
            bv[nt] = *(const h8*)&G1s[(nt*16 + lr) * 1032 + s * 32 + lg * 8];
        #pragma unroll
        for (int mt = 0; mt < 2; ++mt) {
            unsigned int z1u = Zs1[(wid*32 + mt*16 + lr) * 33 + s];
            h2 z1h2 = __builtin_bit_cast(h2, z1u);
            AF af;
            af.q[0] = z1h2 * a0h[mt][0];
            af.q[1] = z1h2 * a0h[mt][1];
            af.q[2] = z1h2 * a0h[mt][2];
            af.q[3] = z1h2 * a0h[mt][3];
            acc[mt][0] = __builtin_amdgcn_mfma_f32_16x16x32_f16(af.v, bv[0], acc[mt][0], 0, 0, 0);
            acc[mt][1] = __builtin_amdgcn_mfma_f32_16x16x32_f16(af.v, bv[1], acc[mt][1], 0, 0, 0);
        }
    }
    #pragma unroll
    for (int mt = 0; mt < 2; ++mt)
        #pragma unroll
        for (int nt = 0; nt < 2; ++nt)
            #pragma unroll
            for (int i = 0; i < 4; ++i)
                T[(size_t)(m0 + wid*32 + mt*16 + lg*4 + i) * 64 + nt*16 + lr] = acc[mt][nt][i];
}

// t2 via f16 MFMA.
__global__ __launch_bounds__(256) void kron_t2_mfma(
    const float* __restrict__ Z, const _Float16* __restrict__ G2h, float* __restrict__ T)
{
    __shared__ __align__(16) unsigned char smem[33792];
    unsigned int* Zs1 = (unsigned int*)smem;
    _Float16*    Bs  = (_Float16*)(smem + 16896);
    float*       Ms  = (float*)smem;

    const int t  = threadIdx.x;
    const int n0 = blockIdx.x * 64;
    const int m0 = blockIdx.y * 128;
    const int wid = t >> 6, lane = t & 63;
    const int wm0 = (wid >> 1) * 64, wn0 = (wid & 1) * 32;
    const int lr = lane & 15, lg = lane >> 4;

    {
        int row = t >> 1, c0 = (t & 1) * 16;
        const f4* zp = (const f4*)(Z + (size_t)(m0 + row) * 192 + 128 + c0);
        unsigned int* dst = Zs1 + row * 33 + c0;
        #pragma unroll
        for (int q = 0; q < 4; ++q) {
            f4 v = zp[q];
            #pragma unroll
            for (int j = 0; j < 4; ++j) {
                _Float16 h = (_Float16)v[j];
                unsigned short us = __builtin_bit_cast(unsigned short, h);
                dst[q * 4 + j] = (unsigned int)us * 0x00010001u;
            }
        }
    }
    h2 a0h[4][4];
    #pragma unroll
    for (int mt = 0; mt < 4; ++mt) {
        const float* zp = Z + (size_t)(m0 + wm0 + mt*16 + lr) * 192 + 96 + lg * 8;
        f4 v0 = *(const f4*)zp, v1 = *(const f4*)(zp + 4);
        a0h[mt][0] = h2{ (_Float16)v0[0], (_Float16)v0[1] };
        a0h[mt][1] = h2{ (_Float16)v0[2], (_Float16)v0[3] };
        a0h[mt][2] = h2{ (_Float16)v1[0], (_Float16)v1[1] };
        a0h[mt][3] = h2{ (_Float16)v1[2], (_Float16)v1[3] };
    }

    f4 acc[4][2];
    #pragma unroll
    for (int mt = 0; mt < 4; ++mt)
        #pragma unroll
        for (int nt = 0; nt < 2; ++nt) acc[mt][nt] = f4{0.f, 0.f, 0.f, 0.f};

    const int brow = t >> 2, bg = t & 3;
    const f4* gsrc = (const f4*)(G2h + (size_t)(n0 + brow) * 1024 + bg * 8);
    f4 breg = gsrc[0];
    int cur = 0;
    for (int s = 0; s < 32; ++s) {
        f4 bnext;
        if (s + 1 < 32) bnext = gsrc[(s + 1) * 4];
        *(f4*)&Bs[cur * 2560 + brow * 40 + bg * 8] = breg;
        __syncthreads();
        h8 bf0 = *(const h8*)&Bs[cur * 2560 + (wn0 + lr) * 40 + lg * 8];
        h8 bf1 = *(const h8*)&Bs[cur * 2560 + (wn0 + 16 + lr) * 40 + lg * 8];
        #pragma unroll
        for (int mt = 0; mt < 4; ++mt) {
            unsigned int z1u = Zs1[(wm0 + mt*16 + lr) * 33 + s];
            h2 z1h2 = __builtin_bit_cast(h2, z1u);
            AF af;
            af.q[0] = z1h2 * a0h[mt][0];
            af.q[1] = z1h2 * a0h[mt][1];
            af.q[2] = z1h2 * a0h[mt][2];
            af.q[3] = z1h2 * a0h[mt][3];
            acc[mt][0] = __builtin_amdgcn_mfma_f32_16x16x32_f16(af.v, bf0, acc[mt][0], 0, 0, 0);
            acc[mt][1] = __builtin_amdgcn_mfma_f32_16x16x32_f16(af.v, bf1, acc[mt][1], 0, 0, 0);
        }
        breg = bnext;
        cur ^= 1;
    }

    __syncthreads();
    #pragma unroll
    for (int mt = 0; mt < 4; ++mt)
        #pragma unroll
        for (int nt = 0; nt < 2; ++nt)
            #pragma unroll
            for (int i = 0; i < 4; ++i)
                Ms[(wm0 + mt*16 + lg*4 + i) * 66 + wn0 + nt*16 + lr] = acc[mt][nt][i];
    __syncthreads();
    {
        int row = t >> 1, rl = t & 1;
        const float* z2p = Z + (size_t)(m0 + row) * 192 + 160;
        const float* mrow = Ms + row * 66 + rl * 32;
        float sum = 0.f;
        #pragma unroll
        for (int r2 = 0; r2 < 32; ++r2) sum += mrow[r2] * z2p[r2];
        T[(size_t)(m0 + row) * 64 + 32 + (n0 >> 5) + rl] = sum;
    }
}

// Y = const + [Z(:,0:32) | T] @ Och^T  via f16 MFMA. K=96 single pass.
// BM=BN=128, grid (8,32) = 256 blocks, 4 waves 2x2, wave tile 64x64.
__global__ __launch_bounds__(256) void gemm_y_mfma(
    const float* __restrict__ Z, const float* __restrict__ T,
    const _Float16* __restrict__ Och, const float* __restrict__ cst,
    float* __restrict__ Y)
{
    __shared__ _Float16 As[128 * 104];
    __shared__ _Float16 Bs[128 * 104];
    const int t = threadIdx.x;
    const int n0 = blockIdx.x * 128, m0 = blockIdx.y * 128;

    {   // stage A = [z00 | t1 | t2] as f16, row pitch 104
        int row = t >> 1, half = t & 1;
        _Float16* dst = As + row * 104;
        if (half == 0) {
            const f4* zp = (const f4*)(Z + (size_t)(m0 + row) * 192);
            #pragma unroll
            for (int q = 0; q < 8; ++q) {
                f4 v = zp[q];
                h4 h = { (_Float16)v[0], (_Float16)v[1], (_Float16)v[2], (_Float16)v[3] };
                *(h4*)(dst + q * 4) = h;
            }
            const f4* tp = (const f4*)(T + (size_t)(m0 + row) * 64);
            #pragma unroll
            for (int q = 0; q < 4; ++q) {
                f4 v = tp[q];
                h4 h = { (_Float16)v[0], (_Float16)v[1], (_Float16)v[2], (_Float16)v[3] };
                *(h4*)(dst + 32 + q * 4) = h;
            }
        } else {
            const f4* tp = (const f4*)(T + (size_t)(m0 + row) * 64 + 16);
            #pragma unroll
            for (int q = 0; q < 12; ++q) {
                f4 v = tp[q];
                h4 h = { (_Float16)v[0], (_Float16)v[1], (_Float16)v[2], (_Float16)v[3] };
                *(h4*)(dst + 48 + q * 4) = h;
            }
        }
    }
    {   // stage B = Och rows n0..n0+127
        int row = t >> 1, half = t & 1;
        const h8* src = (const h8*)(Och + (size_t)(n0 + row) * 96 + half * 48);
        _Float16* dst = Bs + row * 104 + half * 48;
        #pragma unroll
        for (int q = 0; q < 6; ++q) *(h8*)(dst + q * 8) = src[q];
    }
    const int wid = t >> 6, lane = t & 63;
    const int wr = wid >> 1, wc = wid & 1;
    const int lr = lane & 15, lg = lane >> 4;
    float bias[4];
    #pragma unroll
    for (int nt = 0; nt < 4; ++nt) bias[nt] = cst[n0 + wc*64 + nt*16 + lr];
    __syncthreads();

    f4 acc[4][4];
    #pragma unroll
    for (int mt = 0; mt < 4; ++mt)
        #pragma unroll
        for (int nt = 0; nt < 4; ++nt) acc[mt][nt] = f4{0.f,0.f,0.f,0.f};

    #pragma unroll
    for (int ks = 0; ks < 3; ++ks) {
        h8 av[4], bv[4];
        #pragma unroll
        for (int mt = 0; mt < 4; ++mt)
            av[mt] = *(const h8*)&As[(wr*64 + mt*16 + lr) * 104 + ks*32 + lg*8];
        #pragma unroll
        for (int nt = 0; nt < 4; ++nt)
            bv[nt] = *(const h8*)&Bs[(wc*64 + nt*16 + lr) * 104 + ks*32 + lg*8];
        #pragma unroll
        for (int mt = 0; mt < 4; ++mt)
            #pragma unroll
            for (int nt = 0; nt < 4; ++nt)
                acc[mt][nt] = __builtin_amdgcn_mfma_f32_16x16x32_f16(av[mt], bv[nt], acc[mt][nt], 0, 0, 0);
    }
    #pragma unroll
    for (int mt = 0; mt < 4; ++mt)
        #pragma unroll
        for (int nt = 0; nt < 4; ++nt)
            #pragma unroll
            for (int i = 0; i < 4; ++i)
                Y[(size_t)(m0 + wr*64 + mt*16 + lg*4 + i) * 1024 + n0 + wc*64 + nt*16 + lr]
                    = acc[mt][nt][i] + bias[nt];
}

extern "C" void kernel_launch(void* const* d_in, const int* in_sizes, int n_in,
                              void* d_out, int out_size, void* d_ws, size_t ws_size,
                              hipStream_t stream) {
    const float* X   = (const float*)d_in[0];
    const float* cst = (const float*)d_in[1];
    const float* O0  = (const float*)d_in[2];
    const float* I0  = (const float*)d_in[3];
    const float* G0  = (const float*)d_in[4];
    const float* O1  = (const float*)d_in[5];
    const float* I1  = (const float*)d_in[6];
    const float* G1  = (const float*)d_in[7];
    const float* O2  = (const float*)d_in[8];
    const float* I2  = (const float*)d_in[9];
    const float* G2  = (const float*)d_in[10];
    float* ws = (float*)d_ws;
    float* Z  = ws + Z_OFF;
    float* T  = ws + T_OFF;
    _Float16* Wh = (_Float16*)(ws + WH_OFF);
    _Float16* Oh = (_Float16*)(ws + OC_OFF);
    _Float16* G2h = (_Float16*)(ws + G2H_OFF);
    float* Y  = (float*)d_out;

    concat_all<<<2176, 256, 0, stream>>>(I0, I1, I2, O0, O1, O2, G0, G2, Wh, Oh, G2h);
    gemm_x_mfma<<<192, 256, 0, stream>>>(X, Wh, Z);
    kron_t1_mfma<<<32, 256, 0, stream>>>(Z, G1, T);
    kron_t2_mfma<<<dim3(16, 32), 256, 0, stream>>>(Z, G2h, T);
    gemm_y_mfma<<<dim3(8, 32), 256, 0, stream>>>(Z, T, Oh, cst, Y);
}

// Round 9
// 54.094 us; speedup vs baseline: 3.6031x; 1.0206x over previous
//
#include <hip/hip_runtime.h>

// Fast Tucker-Taylor forward. Round 9: round-8 pipeline with the Zs1 staging
// rewritten INTEGER-ONLY (uint4 loads + mask/shift) — no _Float16 ext_vector
// element extraction anywhere (suspected miscompile in rounds 5-8).
//
//   K1 concat_all : Wch(192,1024)f16, Och(1024,96)f16, G2h f16
//   K2 gemm_x     : Z(4096,192)f16 = X @ Wch^T
//   K3 kron_t1    : T(:,0..31)  = kron(z11,z10) @ G1^T      (grid 32)
//   K4 kron_t2    : T(:,32..63) = (kron(z21,z20)@G2m^T).z22 (grid 16x32)
//   K5 gemm_y     : Y = const + [z00|T] @ Och^T  (K=96)
//
// Z f16 cols: z00 0..31 | z10 32..63 | z11 64..95 | z20 96..127 | z21 128..159 | z22 160..191

typedef float f4 __attribute__((ext_vector_type(4)));
typedef _Float16 h8 __attribute__((ext_vector_type(8)));
typedef _Float16 h4 __attribute__((ext_vector_type(4)));
typedef unsigned int u32x4 __attribute__((ext_vector_type(4)));

// ws byte offsets
#define ZH_OFF  0u           // 4096*192 f16 = 1,572,864 B
#define TH_OFF  1572864u     // 4096*64 f16  =   524,288 B
#define WH_OFF  2097152u     // 192*1024 f16 =   393,216 B
#define OCH_OFF 2490368u     // 1024*96 f16  =   196,608 B
#define G2H_OFF 2686976u     // 1024*1024 f16 = 2,097,152 B (end 4,784,128)

__device__ __forceinline__ h8 splat8(unsigned int u) {
    _Float16 s = __builtin_bit_cast(_Float16, (unsigned short)(u & 0xffffu));
    return h8{ s, s, s, s, s, s, s, s };
}

// ---------------- K1: concat ----------------
// blocks 0..1151: Wch + Och; blocks 1152..2175: G2 -> f16
__global__ __launch_bounds__(256) void concat_all(
    const float* __restrict__ I0, const float* __restrict__ I1, const float* __restrict__ I2,
    const float* __restrict__ O0, const float* __restrict__ O1, const float* __restrict__ O2,
    const float* __restrict__ G0, const float* __restrict__ G2,
    _Float16* __restrict__ Wch, _Float16* __restrict__ Och, _Float16* __restrict__ G2h)
{
    if (blockIdx.x >= 1152) {
        int i = ((blockIdx.x - 1152) * 256 + threadIdx.x) * 4;
        f4 v = *(const f4*)(G2 + i);
        h4 o = { (_Float16)v[0], (_Float16)v[1], (_Float16)v[2], (_Float16)v[3] };
        *(h4*)(G2h + i) = o;
        return;
    }
    int gid = blockIdx.x * 256 + threadIdx.x;
    if (gid < 196608) {
        float v;
        if (gid < 32768)      v = I0[gid];
        else if (gid < 98304) v = I1[gid - 32768];
        else                  v = I2[gid - 98304];
        Wch[gid] = (_Float16)v;
    } else {
        int idx = gid - 196608;
        if (idx < 98304) {
            int o = idx / 96, j = idx % 96;
            float v;
            if (j < 32) {
                v = 0.f;
                #pragma unroll
                for (int q = 0; q < 32; ++q) v += O0[o*32 + q] * G0[q*32 + j];
            } else if (j < 64) v = O1[o*32 + (j - 32)];
            else               v = O2[o*32 + (j - 64)];
            Och[idx] = (_Float16)v;
        }
    }
}

// ---------------- K2: Z = f16( X @ Wch^T ) ----------------
__global__ __launch_bounds__(256) void gemm_x_mfma(
    const float* __restrict__ X, const _Float16* __restrict__ Wch,
    _Float16* __restrict__ Z)
{
    __shared__ _Float16 As[64 * 64];
    __shared__ _Float16 Bs[64 * 64];
    const int t = threadIdx.x;
    const int hw = blockIdx.x;
    const int work = (hw & 7) * 24 + (hw >> 3);
    const int m0 = (work / 3) * 64, n0 = (work % 3) * 64;
    const int wid = t >> 6, lane = t & 63;
    const int wr = wid >> 1, wc = wid & 1;
    const int lr = lane & 15, lg = lane >> 4;
    const int arow = t >> 2, aq = t & 3;

    const float*    xbase = X   + (size_t)(m0 + arow) * 1024 + aq * 16;
    const _Float16* wbase = Wch + (size_t)(n0 + arow) * 1024 + aq * 16;
    const int sw0 = arow * 64 + (((aq * 2)     ^ (arow & 7)) << 3);
    const int sw1 = arow * 64 + (((aq * 2 + 1) ^ (arow & 7)) << 3);

    f4 xa[4]; h8 wb[2];
    #pragma unroll
    for (int q = 0; q < 4; ++q) xa[q] = *(const f4*)(xbase + q * 4);
    wb[0] = *(const h8*)wbase;
    wb[1] = *(const h8*)(wbase + 8);

    f4 acc[2][2];
    #pragma unroll
    for (int mt = 0; mt < 2; ++mt)
        #pragma unroll
        for (int nt = 0; nt < 2; ++nt) acc[mt][nt] = f4{0.f,0.f,0.f,0.f};

    for (int s = 0; s < 16; ++s) {
        h8 ha0, ha1;
        #pragma unroll
        for (int j = 0; j < 4; ++j) {
            ha0[j] = (_Float16)xa[0][j]; ha0[4+j] = (_Float16)xa[1][j];
            ha1[j] = (_Float16)xa[2][j]; ha1[4+j] = (_Float16)xa[3][j];
        }
        *(h8*)&As[sw0] = ha0;
        *(h8*)&As[sw1] = ha1;
        *(h8*)&Bs[sw0] = wb[0];
        *(h8*)&Bs[sw1] = wb[1];
        __syncthreads();
        if (s < 15) {
            const float* xp = xbase + (s + 1) * 64;
            #pragma unroll
            for (int q = 0; q < 4; ++q) xa[q] = *(const f4*)(xp + q * 4);
            wb[0] = *(const h8*)(wbase + (s + 1) * 64);
            wb[1] = *(const h8*)(wbase + (s + 1) * 64 + 8);
        }
        #pragma unroll
        for (int ks = 0; ks < 2; ++ks) {
            h8 av[2], bv[2];
            #pragma unroll
            for (int mt = 0; mt < 2; ++mt) {
                int row = wr * 32 + mt * 16 + lr, gg = ks * 4 + lg;
                av[mt] = *(const h8*)&As[row * 64 + ((gg ^ (row & 7)) << 3)];
            }
            #pragma unroll
            for (int nt = 0; nt < 2; ++nt) {
                int row = wc * 32 + nt * 16 + lr, gg = ks * 4 + lg;
                bv[nt] = *(const h8*)&Bs[row * 64 + ((gg ^ (row & 7)) << 3)];
            }
            #pragma unroll
            for (int mt = 0; mt < 2; ++mt)
                #pragma unroll
                for (int nt = 0; nt < 2; ++nt)
                    acc[mt][nt] = __builtin_amdgcn_mfma_f32_16x16x32_f16(av[mt], bv[nt], acc[mt][nt], 0, 0, 0);
        }
        __syncthreads();
    }
    #pragma unroll
    for (int mt = 0; mt < 2; ++mt)
        #pragma unroll
        for (int nt = 0; nt < 2; ++nt)
            #pragma unroll
            for (int i = 0; i < 4; ++i)
                Z[(size_t)(m0 + wr*32 + mt*16 + lg*4 + i) * 192 + n0 + wc*32 + nt*16 + lr]
                    = (_Float16)acc[mt][nt][i];
}

// Integer-only broadcast-pair staging: reads 16 halves (as 2 x uint4) from
// zsrc, writes 16 u32 broadcast pairs to dst (dst[k] = half k duplicated).
__device__ __forceinline__ void stage_bcast16(const _Float16* zsrc, unsigned int* dst) {
    u32x4 u0 = *(const u32x4*)zsrc;
    u32x4 u1 = *(const u32x4*)(zsrc + 8);
    #pragma unroll
    for (int k = 0; k < 4; ++k) {
        dst[2*k]       = (u0[k] & 0xffffu) * 0x00010001u;
        dst[2*k + 1]   = (u0[k] >> 16)     * 0x00010001u;
        dst[8 + 2*k]   = (u1[k] & 0xffffu) * 0x00010001u;
        dst[8 + 2*k+1] = (u1[k] >> 16)     * 0x00010001u;
    }
}

// ---------------- K3: t1 = kron(z11,z10) @ G1^T ----------------
__global__ __launch_bounds__(256) void kron_t1_mfma(
    const _Float16* __restrict__ Z, const float* __restrict__ G1, _Float16* __restrict__ T)
{
    __shared__ __align__(16) unsigned char smem[16896 + 66048];
    unsigned int* Zs1 = (unsigned int*)smem;            // [128][33] z11 broadcast pairs
    _Float16* G1s = (_Float16*)(smem + 16896);          // [32][1032]
    const int t = threadIdx.x;
    const int m0 = blockIdx.x * 128;
    const int wid = t >> 6, lane = t & 63;
    const int lr = lane & 15, lg = lane >> 4;

    {   // z11 (cols 64..95) -> broadcast u32 pairs (integer-only)
        int row = t >> 1, c0 = (t & 1) * 16;
        stage_bcast16(Z + (size_t)(m0 + row) * 192 + 64 + c0, Zs1 + row * 33 + c0);
    }
    {   // G1 fp32 -> f16 LDS (whole matrix)
        #pragma unroll
        for (int j = 0; j < 32; ++j) {
            int flat = j * 1024 + t * 4;
            f4 v = *(const f4*)(G1 + flat);
            int row = flat >> 10, col = flat & 1023;
            h4 h = { (_Float16)v[0], (_Float16)v[1], (_Float16)v[2], (_Float16)v[3] };
            *(h4*)&G1s[row * 1032 + col] = h;
        }
    }
    // z10 (cols 32..63) register frags — plain h8 whole-vector loads
    h8 a0v[2];
    #pragma unroll
    for (int mt = 0; mt < 2; ++mt)
        a0v[mt] = *(const h8*)(Z + (size_t)(m0 + wid*32 + mt*16 + lr) * 192 + 32 + lg * 8);
    __syncthreads();

    f4 acc[2][2];
    #pragma unroll
    for (int mt = 0; mt < 2; ++mt)
        #pragma unroll
        for (int nt = 0; nt < 2; ++nt) acc[mt][nt] = f4{0.f,0.f,0.f,0.f};

    for (int s = 0; s < 32; ++s) {
        h8 bv[2];
        #pragma unroll
        for (int nt = 0; nt < 2; ++nt)
            bv[nt] = *(const h8*)&G1s[(nt*16 + lr) * 1032 + s * 32 + lg * 8];
        #pragma unroll
        for (int mt = 0; mt < 2; ++mt) {
            h8 z1b = splat8(Zs1[(wid*32 + mt*16 + lr) * 33 + s]);
            h8 af = z1b * a0v[mt];
            acc[mt][0] = __builtin_amdgcn_mfma_f32_16x16x32_f16(af, bv[0], acc[mt][0], 0, 0, 0);
            acc[mt][1] = __builtin_amdgcn_mfma_f32_16x16x32_f16(af, bv[1], acc[mt][1], 0, 0, 0);
        }
    }
    #pragma unroll
    for (int mt = 0; mt < 2; ++mt)
        #pragma unroll
        for (int nt = 0; nt < 2; ++nt)
            #pragma unroll
            for (int i = 0; i < 4; ++i)
                T[(size_t)(m0 + wid*32 + mt*16 + lg*4 + i) * 64 + nt*16 + lr]
                    = (_Float16)acc[mt][nt][i];
}

// ---------------- K4: t2 ----------------
__global__ __launch_bounds__(256) void kron_t2_mfma(
    const _Float16* __restrict__ Z, const _Float16* __restrict__ G2h, _Float16* __restrict__ T)
{
    __shared__ __align__(16) unsigned char smem[33792];
    unsigned int* Zs1 = (unsigned int*)smem;            // [128][33]
    _Float16*    Bs  = (_Float16*)(smem + 16896);       // [2][64][40]
    float*       Ms  = (float*)smem;                    // [128][66] epilogue reuse

    const int t  = threadIdx.x;
    const int n0 = blockIdx.x * 64;
    const int m0 = blockIdx.y * 128;
    const int wid = t >> 6, lane = t & 63;
    const int wm0 = (wid >> 1) * 64, wn0 = (wid & 1) * 32;
    const int lr = lane & 15, lg = lane >> 4;

    {   // z21 (cols 128..159) -> broadcast u32 pairs (integer-only)
        int row = t >> 1, c0 = (t & 1) * 16;
        stage_bcast16(Z + (size_t)(m0 + row) * 192 + 128 + c0, Zs1 + row * 33 + c0);
    }
    // z20 (cols 96..127) register frags — plain h8 whole-vector loads
    h8 a0v[4];
    #pragma unroll
    for (int mt = 0; mt < 4; ++mt)
        a0v[mt] = *(const h8*)(Z + (size_t)(m0 + wm0 + mt*16 + lr) * 192 + 96 + lg * 8);

    f4 acc[4][2];
    #pragma unroll
    for (int mt = 0; mt < 4; ++mt)
        #pragma unroll
        for (int nt = 0; nt < 2; ++nt) acc[mt][nt] = f4{0.f, 0.f, 0.f, 0.f};

    const int brow = t >> 2, bg = t & 3;
    const f4* gsrc = (const f4*)(G2h + (size_t)(n0 + brow) * 1024 + bg * 8);
    f4 breg = gsrc[0];
    int cur = 0;
    for (int s = 0; s < 32; ++s) {
        f4 bnext;
        if (s + 1 < 32) bnext = gsrc[(s + 1) * 4];
        *(f4*)&Bs[cur * 2560 + brow * 40 + bg * 8] = breg;
        __syncthreads();
        h8 bf0 = *(const h8*)&Bs[cur * 2560 + (wn0 + lr) * 40 + lg * 8];
        h8 bf1 = *(const h8*)&Bs[cur * 2560 + (wn0 + 16 + lr) * 40 + lg * 8];
        #pragma unroll
        for (int mt = 0; mt < 4; ++mt) {
            h8 z1b = splat8(Zs1[(wm0 + mt*16 + lr) * 33 + s]);
            h8 af = z1b * a0v[mt];
            acc[mt][0] = __builtin_amdgcn_mfma_f32_16x16x32_f16(af, bf0, acc[mt][0], 0, 0, 0);
            acc[mt][1] = __builtin_amdgcn_mfma_f32_16x16x32_f16(af, bf1, acc[mt][1], 0, 0, 0);
        }
        breg = bnext;
        cur ^= 1;
    }

    __syncthreads();
    #pragma unroll
    for (int mt = 0; mt < 4; ++mt)
        #pragma unroll
        for (int nt = 0; nt < 2; ++nt)
            #pragma unroll
            for (int i = 0; i < 4; ++i)
                Ms[(wm0 + mt*16 + lg*4 + i) * 66 + wn0 + nt*16 + lr] = acc[mt][nt][i];
    __syncthreads();
    {
        int row = t >> 1, rl = t & 1;
        const _Float16* z2p = Z + (size_t)(m0 + row) * 192 + 160;
        const float* mrow = Ms + row * 66 + rl * 32;
        float sum = 0.f;
        #pragma unroll
        for (int r2 = 0; r2 < 32; ++r2) sum += mrow[r2] * (float)z2p[r2];
        T[(size_t)(m0 + row) * 64 + 32 + (n0 >> 5) + rl] = (_Float16)sum;
    }
}

// ---------------- K5: Y = const + [z00|T] @ Och^T ----------------
__global__ __launch_bounds__(256) void gemm_y_mfma(
    const _Float16* __restrict__ Z, const _Float16* __restrict__ T,
    const _Float16* __restrict__ Och, const float* __restrict__ cst,
    float* __restrict__ Y)
{
    __shared__ _Float16 As[128 * 104];
    __shared__ _Float16 Bs[128 * 104];
    const int t = threadIdx.x;
    const int n0 = blockIdx.x * 128, m0 = blockIdx.y * 128;
    {
        int row = t >> 1, half = t & 1;
        _Float16* dst = As + row * 104 + half * 48;
        if (half == 0) {
            const _Float16* zp = Z + (size_t)(m0 + row) * 192;
            *(h8*)dst        = *(const h8*)zp;
            *(h8*)(dst + 8)  = *(const h8*)(zp + 8);
            *(h8*)(dst + 16) = *(const h8*)(zp + 16);
            *(h8*)(dst + 24) = *(const h8*)(zp + 24);
            const _Float16* tp = T + (size_t)(m0 + row) * 64;
            *(h8*)(dst + 32) = *(const h8*)tp;
            *(h8*)(dst + 40) = *(const h8*)(tp + 8);
        } else {
            const _Float16* tp = T + (size_t)(m0 + row) * 64 + 16;
            #pragma unroll
            for (int q = 0; q < 6; ++q) *(h8*)(dst + q * 8) = *(const h8*)(tp + q * 8);
        }
        const _Float16* src = Och + (size_t)(n0 + row) * 96 + half * 48;
        _Float16* bdst = Bs + row * 104 + half * 48;
        #pragma unroll
        for (int q = 0; q < 6; ++q) *(h8*)(bdst + q * 8) = *(const h8*)(src + q * 8);
    }
    const int wid = t >> 6, lane = t & 63;
    const int wvr = wid >> 1, wvc = wid & 1;
    const int lr = lane & 15, lg = lane >> 4;
    float bias[4];
    #pragma unroll
    for (int nt = 0; nt < 4; ++nt) bias[nt] = cst[n0 + wvc*64 + nt*16 + lr];
    __syncthreads();

    f4 acc[4][4];
    #pragma unroll
    for (int mt = 0; mt < 4; ++mt)
        #pragma unroll
        for (int nt = 0; nt < 4; ++nt) acc[mt][nt] = f4{0.f,0.f,0.f,0.f};

    #pragma unroll
    for (int ks = 0; ks < 3; ++ks) {
        h8 av[4], bv[4];
        #pragma unroll
        for (int mt = 0; mt < 4; ++mt)
            av[mt] = *(const h8*)&As[(wvr*64 + mt*16 + lr) * 104 + ks*32 + lg*8];
        #pragma unroll
        for (int nt = 0; nt < 4; ++nt)
            bv[nt] = *(const h8*)&Bs[(wvc*64 + nt*16 + lr) * 104 + ks*32 + lg*8];
        #pragma unroll
        for (int mt = 0; mt < 4; ++mt)
            #pragma unroll
            for (int nt = 0; nt < 4; ++nt)
                acc[mt][nt] = __builtin_amdgcn_mfma_f32_16x16x32_f16(av[mt], bv[nt], acc[mt][nt], 0, 0, 0);
    }
    #pragma unroll
    for (int mt = 0; mt < 4; ++mt)
        #pragma unroll
        for (int nt = 0; nt < 4; ++nt)
            #pragma unroll
            for (int i = 0; i < 4; ++i)
                Y[(size_t)(m0 + wvr*64 + mt*16 + lg*4 + i) * 1024 + n0 + wvc*64 + nt*16 + lr]
                    = acc[mt][nt][i] + bias[nt];
}

extern "C" void kernel_launch(void* const* d_in, const int* in_sizes, int n_in,
                              void* d_out, int out_size, void* d_ws, size_t ws_size,
                              hipStream_t stream) {
    const float* X   = (const float*)d_in[0];
    const float* cst = (const float*)d_in[1];
    const float* O0  = (const float*)d_in[2];
    const float* I0  = (const float*)d_in[3];
    const float* G0  = (const float*)d_in[4];
    const float* O1  = (const float*)d_in[5];
    const float* I1  = (const float*)d_in[6];
    const float* G1  = (const float*)d_in[7];
    const float* O2  = (const float*)d_in[8];
    const float* I2  = (const float*)d_in[9];
    const float* G2  = (const float*)d_in[10];
    unsigned char* ws = (unsigned char*)d_ws;
    _Float16* Zh  = (_Float16*)(ws + ZH_OFF);
    _Float16* Th  = (_Float16*)(ws + TH_OFF);
    _Float16* Wh  = (_Float16*)(ws + WH_OFF);
    _Float16* Oh  = (_Float16*)(ws + OCH_OFF);
    _Float16* G2h = (_Float16*)(ws + G2H_OFF);
    float* Y = (float*)d_out;

    concat_all<<<2176, 256, 0, stream>>>(I0, I1, I2, O0, O1, O2, G0, G2, Wh, Oh, G2h);
    gemm_x_mfma<<<192, 256, 0, stream>>>(X, Wh, Zh);
    kron_t1_mfma<<<32, 256, 0, stream>>>(Zh, G1, Th);
    kron_t2_mfma<<<dim3(16, 32), 256, 0, stream>>>(Zh, G2h, Th);
    gemm_y_mfma<<<dim3(8, 32), 256, 0, stream>>>(Zh, Th, Oh, cst, Y);
}

// Round 10
// 51.038 us; speedup vs baseline: 3.8188x; 1.0599x over previous
//
#include <hip/hip_runtime.h>

// Fast Tucker-Taylor forward. Round 10: round-5 3-launch pipeline resurrected
// with the miscompile fix (integer-only z1 broadcast staging; no _Float16
// ext_vector element extraction anywhere).
//
//   K1 prep_gemmx : blocks 0..191 Z=f16(X@Wcat^T) (W rows inline from I*);
//                   192..1215 G2h=f16(G2); 1216..1599 Och=[O0G0|O1|O2] f16
//   K2 kron_fused : blocks 0..255 t2 (BM=128,BN=128, 1 barrier/K-step,
//                   fused z22 contract); 256..287 t1 (BM=128,BN=32)
//   K3 gemm_y     : Y = const + [z00|T] @ Och^T  (K=96)
//
// Z f16 cols: z00 0..31 | z10 32..63 | z11 64..95 | z20 96..127 | z21 128..159 | z22 160..191

typedef float f4 __attribute__((ext_vector_type(4)));
typedef _Float16 h8 __attribute__((ext_vector_type(8)));
typedef _Float16 h4 __attribute__((ext_vector_type(4)));
typedef unsigned int u32x4 __attribute__((ext_vector_type(4)));

// ws byte offsets
#define ZH_OFF  0u           // 4096*192 f16 = 1,572,864 B
#define TH_OFF  1572864u     // 4096*64 f16  =   524,288 B
#define OCH_OFF 2097152u     // 1024*96 f16  =   196,608 B
#define G2H_OFF 2293760u     // 1024*1024 f16 = 2,097,152 B (end 4,390,912)

__device__ __forceinline__ h8 splat8(unsigned int u) {
    _Float16 s = __builtin_bit_cast(_Float16, (unsigned short)(u & 0xffffu));
    return h8{ s, s, s, s, s, s, s, s };
}

// Integer-only broadcast-pair staging: reads 16 halves (2 x uint4) from zsrc,
// writes 16 u32 broadcast pairs to dst (dst[k] = half k duplicated in lo+hi).
__device__ __forceinline__ void stage_bcast16(const _Float16* zsrc, unsigned int* dst) {
    u32x4 u0 = *(const u32x4*)zsrc;
    u32x4 u1 = *(const u32x4*)(zsrc + 8);
    #pragma unroll
    for (int k = 0; k < 4; ++k) {
        dst[2*k]       = (u0[k] & 0xffffu) * 0x00010001u;
        dst[2*k + 1]   = (u0[k] >> 16)     * 0x00010001u;
        dst[8 + 2*k]   = (u1[k] & 0xffffu) * 0x00010001u;
        dst[8 + 2*k+1] = (u1[k] >> 16)     * 0x00010001u;
    }
}

// ---------------- K1: prep + X-GEMM ----------------
__global__ __launch_bounds__(256) void prep_gemmx(
    const float* __restrict__ X,
    const float* __restrict__ I0, const float* __restrict__ I1, const float* __restrict__ I2,
    const float* __restrict__ O0, const float* __restrict__ O1, const float* __restrict__ O2,
    const float* __restrict__ G0, const float* __restrict__ G2,
    _Float16* __restrict__ Och, _Float16* __restrict__ G2h, _Float16* __restrict__ Z)
{
    const int bx = blockIdx.x;
    const int t = threadIdx.x;
    if (bx >= 192) {
        if (bx < 1216) {           // G2 -> f16
            int i = ((bx - 192) * 256 + t) * 4;
            f4 v = *(const f4*)(G2 + i);
            h4 o = { (_Float16)v[0], (_Float16)v[1], (_Float16)v[2], (_Float16)v[3] };
            *(h4*)(G2h + i) = o;
        } else {                   // Och
            int idx = (bx - 1216) * 256 + t;
            int o = idx / 96, j = idx - o * 96;
            float v;
            if (j < 32) {
                v = 0.f;
                #pragma unroll
                for (int q = 0; q < 32; ++q) v += O0[o*32 + q] * G0[q*32 + j];
            } else if (j < 64) v = O1[o*32 + (j - 32)];
            else               v = O2[o*32 + (j - 64)];
            Och[idx] = (_Float16)v;
        }
        return;
    }
    // ---- X-GEMM (r9 structure): Z = f16( X @ Wcat^T ), W rows inline from I* ----
    __shared__ _Float16 As[64 * 64];
    __shared__ _Float16 Bs[64 * 64];
    const int work = (bx & 7) * 24 + (bx >> 3);       // XCD-chunked (192=8*24)
    const int m0 = (work / 3) * 64, n0 = (work % 3) * 64;
    const int wid = t >> 6, lane = t & 63;
    const int wr = wid >> 1, wc = wid & 1;
    const int lr = lane & 15, lg = lane >> 4;
    const int arow = t >> 2, aq = t & 3;

    const float* xbase = X + (size_t)(m0 + arow) * 1024 + aq * 16;
    const int wrow = n0 + arow;
    const float* wbase = (wrow < 32) ? I0 + (size_t)wrow * 1024
                       : (wrow < 96) ? I1 + (size_t)(wrow - 32) * 1024
                                     : I2 + (size_t)(wrow - 96) * 1024;
    wbase += aq * 16;
    const int sw0 = arow * 64 + (((aq * 2)     ^ (arow & 7)) << 3);
    const int sw1 = arow * 64 + (((aq * 2 + 1) ^ (arow & 7)) << 3);

    f4 xa[4], wa[4];
    #pragma unroll
    for (int q = 0; q < 4; ++q) { xa[q] = *(const f4*)(xbase + q*4); wa[q] = *(const f4*)(wbase + q*4); }

    f4 acc[2][2];
    #pragma unroll
    for (int mt = 0; mt < 2; ++mt)
        #pragma unroll
        for (int nt = 0; nt < 2; ++nt) acc[mt][nt] = f4{0.f,0.f,0.f,0.f};

    for (int s = 0; s < 16; ++s) {
        h8 ha0, ha1, hb0, hb1;
        #pragma unroll
        for (int j = 0; j < 4; ++j) {
            ha0[j] = (_Float16)xa[0][j]; ha0[4+j] = (_Float16)xa[1][j];
            ha1[j] = (_Float16)xa[2][j]; ha1[4+j] = (_Float16)xa[3][j];
            hb0[j] = (_Float16)wa[0][j]; hb0[4+j] = (_Float16)wa[1][j];
            hb1[j] = (_Float16)wa[2][j]; hb1[4+j] = (_Float16)wa[3][j];
        }
        *(h8*)&As[sw0] = ha0; *(h8*)&As[sw1] = ha1;
        *(h8*)&Bs[sw0] = hb0; *(h8*)&Bs[sw1] = hb1;
        __syncthreads();
        if (s < 15) {
            const float* xp = xbase + (s + 1) * 64;
            const float* wp = wbase + (s + 1) * 64;
            #pragma unroll
            for (int q = 0; q < 4; ++q) { xa[q] = *(const f4*)(xp + q*4); wa[q] = *(const f4*)(wp + q*4); }
        }
        #pragma unroll
        for (int ks = 0; ks < 2; ++ks) {
            h8 av[2], bv[2];
            #pragma unroll
            for (int mt = 0; mt < 2; ++mt) {
                int row = wr * 32 + mt * 16 + lr, gg = ks * 4 + lg;
                av[mt] = *(const h8*)&As[row * 64 + ((gg ^ (row & 7)) << 3)];
            }
            #pragma unroll
            for (int nt = 0; nt < 2; ++nt) {
                int row = wc * 32 + nt * 16 + lr, gg = ks * 4 + lg;
                bv[nt] = *(const h8*)&Bs[row * 64 + ((gg ^ (row & 7)) << 3)];
            }
            #pragma unroll
            for (int mt = 0; mt < 2; ++mt)
                #pragma unroll
                for (int nt = 0; nt < 2; ++nt)
                    acc[mt][nt] = __builtin_amdgcn_mfma_f32_16x16x32_f16(av[mt], bv[nt], acc[mt][nt], 0, 0, 0);
        }
        __syncthreads();
    }
    #pragma unroll
    for (int mt = 0; mt < 2; ++mt)
        #pragma unroll
        for (int nt = 0; nt < 2; ++nt)
            #pragma unroll
            for (int i = 0; i < 4; ++i)
                Z[(size_t)(m0 + wr*32 + mt*16 + lg*4 + i) * 192 + n0 + wc*32 + nt*16 + lr]
                    = (_Float16)acc[mt][nt][i];
}

// ---------------- K2: fused kron t2 + t1 ----------------
// t2 (bx<256): n0=(bx&7)*128, m0=(bx>>3)*128. BM=128,BN=128,BK=32; 4 waves,
//   wave tile 64x64 (16 MFMA/step); 1 barrier/step double-buffered B;
//   fused z22 epilogue. t1 (bx>=256): m0=(bx-256)*128, BN=32.
__global__ __launch_bounds__(256) void kron_fused(
    const _Float16* __restrict__ Z, const _Float16* __restrict__ G2h,
    const float* __restrict__ G1, _Float16* __restrict__ T)
{
    __shared__ __align__(16) unsigned char smem[68096];
    unsigned int* Zs1 = (unsigned int*)smem;               // [128][33] u32 broadcast
    _Float16* Bs = (_Float16*)(smem + 16896);              // [2][128][40] (t1: [2][32][40])
    const int bx = blockIdx.x;
    const int t = threadIdx.x;
    const int wid = t >> 6, lane = t & 63;
    const int lr = lane & 15, lg = lane >> 4;
    const bool is_t2 = bx < 256;
    const int m0 = is_t2 ? (bx >> 3) * 128 : (bx - 256) * 128;
    const int zcol = is_t2 ? 128 : 64;                     // z21 vs z11

    {   // z-outer factor -> broadcast u32 pairs (integer-only)
        int row = t >> 1, c0 = (t & 1) * 16;
        stage_bcast16(Z + (size_t)(m0 + row) * 192 + zcol + c0, Zs1 + row * 33 + c0);
    }

    if (is_t2) {
        const int n0 = (bx & 7) * 128;
        const int wm0 = (wid >> 1) * 64, wn0 = (wid & 1) * 64;
        h8 a0v[4];
        #pragma unroll
        for (int mt = 0; mt < 4; ++mt)
            a0v[mt] = *(const h8*)(Z + (size_t)(m0 + wm0 + mt*16 + lr) * 192 + 96 + lg * 8);

        const int brow = t >> 1, bq = (t & 1) * 16;
        const _Float16* gsrc = G2h + (size_t)(n0 + brow) * 1024 + bq;
        f4 br0 = *(const f4*)gsrc, br1 = *(const f4*)(gsrc + 8);
        *(f4*)&Bs[brow * 40 + bq] = br0;
        *(f4*)&Bs[brow * 40 + bq + 8] = br1;
        br0 = *(const f4*)(gsrc + 32); br1 = *(const f4*)(gsrc + 40);

        f4 acc[4][4];
        #pragma unroll
        for (int mt = 0; mt < 4; ++mt)
            #pragma unroll
            for (int nt = 0; nt < 4; ++nt) acc[mt][nt] = f4{0.f,0.f,0.f,0.f};
        __syncthreads();

        for (int s = 0; s < 32; ++s) {
            const int cur = s & 1;
            if (s < 31) {
                _Float16* bd = &Bs[(cur ^ 1) * 5120 + brow * 40 + bq];
                *(f4*)bd = br0; *(f4*)(bd + 8) = br1;
            }
            if (s < 30) {
                br0 = *(const f4*)(gsrc + (s + 2) * 32);
                br1 = *(const f4*)(gsrc + (s + 2) * 32 + 8);
            }
            h8 bf[4];
            #pragma unroll
            for (int nt = 0; nt < 4; ++nt)
                bf[nt] = *(const h8*)&Bs[cur * 5120 + (wn0 + nt*16 + lr) * 40 + lg * 8];
            #pragma unroll
            for (int mt = 0; mt < 4; ++mt) {
                h8 z1b = splat8(Zs1[(wm0 + mt*16 + lr) * 33 + s]);
                h8 af = z1b * a0v[mt];
                #pragma unroll
                for (int nt = 0; nt < 4; ++nt)
                    acc[mt][nt] = __builtin_amdgcn_mfma_f32_16x16x32_f16(af, bf[nt], acc[mt][nt], 0, 0, 0);
            }
            __syncthreads();
        }
        // epilogue: M-tile -> LDS (pitch 133), contract r2 with z22, write t2
        float* Ms = (float*)smem;                          // [128][133]
        #pragma unroll
        for (int mt = 0; mt < 4; ++mt)
            #pragma unroll
            for (int nt = 0; nt < 4; ++nt)
                #pragma unroll
                for (int i = 0; i < 4; ++i)
                    Ms[(wm0 + mt*16 + lg*4 + i) * 133 + wn0 + nt*16 + lr] = acc[mt][nt][i];
        __syncthreads();
        #pragma unroll
        for (int ss = 0; ss < 2; ++ss) {
            int row = t & 127;
            int rl = (t >> 7) + ss * 2;
            const _Float16* z2p = Z + (size_t)(m0 + row) * 192 + 160;
            float sum = 0.f;
            #pragma unroll
            for (int r2 = 0; r2 < 32; ++r2) sum += Ms[row * 133 + rl * 32 + r2] * (float)z2p[r2];
            T[(size_t)(m0 + row) * 64 + 32 + (bx & 7) * 4 + rl] = (_Float16)sum;
        }
    } else {
        // ---- t1: kron(z11,z10) @ G1^T ----
        h8 a0v[2];
        #pragma unroll
        for (int mt = 0; mt < 2; ++mt)
            a0v[mt] = *(const h8*)(Z + (size_t)(m0 + wid*32 + mt*16 + lr) * 192 + 32 + lg * 8);

        const int brow = t >> 3, bq = (t & 7) * 4;
        const float* g1src = G1 + (size_t)brow * 1024 + bq;
        f4 bw = *(const f4*)g1src;
        {
            h4 bh = { (_Float16)bw[0], (_Float16)bw[1], (_Float16)bw[2], (_Float16)bw[3] };
            *(h4*)&Bs[brow * 40 + bq] = bh;
        }
        bw = *(const f4*)(g1src + 32);

        f4 acc[2][2];
        #pragma unroll
        for (int mt = 0; mt < 2; ++mt)
            #pragma unroll
            for (int nt = 0; nt < 2; ++nt) acc[mt][nt] = f4{0.f,0.f,0.f,0.f};
        __syncthreads();

        for (int s = 0; s < 32; ++s) {
            const int cur = s & 1;
            if (s < 31) {
                h4 bh = { (_Float16)bw[0], (_Float16)bw[1], (_Float16)bw[2], (_Float16)bw[3] };
                *(h4*)&Bs[(cur ^ 1) * 5120 + brow * 40 + bq] = bh;
            }
            if (s < 30) bw = *(const f4*)(g1src + (s + 2) * 32);
            h8 bf[2];
            #pragma unroll
            for (int nt = 0; nt < 2; ++nt)
                bf[nt] = *(const h8*)&Bs[cur * 5120 + (nt*16 + lr) * 40 + lg * 8];
            #pragma unroll
            for (int mt = 0; mt < 2; ++mt) {
                h8 z1b = splat8(Zs1[(wid*32 + mt*16 + lr) * 33 + s]);
                h8 af = z1b * a0v[mt];
                acc[mt][0] = __builtin_amdgcn_mfma_f32_16x16x32_f16(af, bf[0], acc[mt][0], 0, 0, 0);
                acc[mt][1] = __builtin_amdgcn_mfma_f32_16x16x32_f16(af, bf[1], acc[mt][1], 0, 0, 0);
            }
            __syncthreads();
        }
        #pragma unroll
        for (int mt = 0; mt < 2; ++mt)
            #pragma unroll
            for (int nt = 0; nt < 2; ++nt)
                #pragma unroll
                for (int i = 0; i < 4; ++i)
                    T[(size_t)(m0 + wid*32 + mt*16 + lg*4 + i) * 64 + nt*16 + lr]
                        = (_Float16)acc[mt][nt][i];
    }
}

// ---------------- K3: Y = const + [z00|T] @ Och^T ----------------
__global__ __launch_bounds__(256) void gemm_y_mfma(
    const _Float16* __restrict__ Z, const _Float16* __restrict__ T,
    const _Float16* __restrict__ Och, const float* __restrict__ cst,
    float* __restrict__ Y)
{
    __shared__ _Float16 As[128 * 104];
    __shared__ _Float16 Bs[128 * 104];
    const int t = threadIdx.x;
    const int n0 = blockIdx.x * 128, m0 = blockIdx.y * 128;
    {
        int row = t >> 1, half = t & 1;
        _Float16* dst = As + row * 104 + half * 48;
        if (half == 0) {
            const _Float16* zp = Z + (size_t)(m0 + row) * 192;
            *(h8*)dst        = *(const h8*)zp;
            *(h8*)(dst + 8)  = *(const h8*)(zp + 8);
            *(h8*)(dst + 16) = *(const h8*)(zp + 16);
            *(h8*)(dst + 24) = *(const h8*)(zp + 24);
            const _Float16* tp = T + (size_t)(m0 + row) * 64;
            *(h8*)(dst + 32) = *(const h8*)tp;
            *(h8*)(dst + 40) = *(const h8*)(tp + 8);
        } else {
            const _Float16* tp = T + (size_t)(m0 + row) * 64 + 16;
            #pragma unroll
            for (int q = 0; q < 6; ++q) *(h8*)(dst + q * 8) = *(const h8*)(tp + q * 8);
        }
        const _Float16* src = Och + (size_t)(n0 + row) * 96 + half * 48;
        _Float16* bdst = Bs + row * 104 + half * 48;
        #pragma unroll
        for (int q = 0; q < 6; ++q) *(h8*)(bdst + q * 8) = *(const h8*)(src + q * 8);
    }
    const int wid = t >> 6, lane = t & 63;
    const int wvr = wid >> 1, wvc = wid & 1;
    const int lr = lane & 15, lg = lane >> 4;
    float bias[4];
    #pragma unroll
    for (int nt = 0; nt < 4; ++nt) bias[nt] = cst[n0 + wvc*64 + nt*16 + lr];
    __syncthreads();

    f4 acc[4][4];
    #pragma unroll
    for (int mt = 0; mt < 4; ++mt)
        #pragma unroll
        for (int nt = 0; nt < 4; ++nt) acc[mt][nt] = f4{0.f,0.f,0.f,0.f};

    #pragma unroll
    for (int ks = 0; ks < 3; ++ks) {
        h8 av[4], bv[4];
        #pragma unroll
        for (int mt = 0; mt < 4; ++mt)
            av[mt] = *(const h8*)&As[(wvr*64 + mt*16 + lr) * 104 + ks*32 + lg*8];
        #pragma unroll
        for (int nt = 0; nt < 4; ++nt)
            bv[nt] = *(const h8*)&Bs[(wvc*64 + nt*16 + lr) * 104 + ks*32 + lg*8];
        #pragma unroll
        for (int mt = 0; mt < 4; ++mt)
            #pragma unroll
            for (int nt = 0; nt < 4; ++nt)
                acc[mt][nt] = __builtin_amdgcn_mfma_f32_16x16x32_f16(av[mt], bv[nt], acc[mt][nt], 0, 0, 0);
    }
    #pragma unroll
    for (int mt = 0; mt < 4; ++mt)
        #pragma unroll
        for (int nt = 0; nt < 4; ++nt)
            #pragma unroll
            for (int i = 0; i < 4; ++i)
                Y[(size_t)(m0 + wvr*64 + mt*16 + lg*4 + i) * 1024 + n0 + wvc*64 + nt*16 + lr]
                    = acc[mt][nt][i] + bias[nt];
}

extern "C" void kernel_launch(void* const* d_in, const int* in_sizes, int n_in,
                              void* d_out, int out_size, void* d_ws, size_t ws_size,
                              hipStream_t stream) {
    const float* X   = (const float*)d_in[0];
    const float* cst = (const float*)d_in[1];
    const float* O0  = (const float*)d_in[2];
    const float* I0  = (const float*)d_in[3];
    const float* G0  = (const float*)d_in[4];
    const float* O1  = (const float*)d_in[5];
    const float* I1  = (const float*)d_in[6];
    const float* G1  = (const float*)d_in[7];
    const float* O2  = (const float*)d_in[8];
    const float* I2  = (const float*)d_in[9];
    const float* G2  = (const float*)d_in[10];
    unsigned char* ws = (unsigned char*)d_ws;
    _Float16* Zh  = (_Float16*)(ws + ZH_OFF);
    _Float16* Th  = (_Float16*)(ws + TH_OFF);
    _Float16* Oh  = (_Float16*)(ws + OCH_OFF);
    _Float16* G2h = (_Float16*)(ws + G2H_OFF);
    float* Y = (float*)d_out;

    prep_gemmx<<<1600, 256, 0, stream>>>(X, I0, I1, I2, O0, O1, O2, G0, G2, Oh, G2h, Zh);
    kron_fused<<<288, 256, 0, stream>>>(Zh, G2h, G1, Th);
    gemm_y_mfma<<<dim3(8, 32), 256, 0, stream>>>(Zh, Th, Oh, cst, Y);
}

// Round 11
// 47.602 us; speedup vs baseline: 4.0945x; 1.0722x over previous
//
#include <hip/hip_runtime.h>

// Fast Tucker-Taylor forward. Round 11: occupancy round.
//   K1 prep_gemmx : blocks 0..191 Z=f16(X@Wcat^T) (W rows inline from I*);
//                   192..1215 G2h=f16(G2); 1216..1599 Och=[O0G0|O1|O2] f16
//   K2 kron_fused : blocks 0..511 t2 (BM=128,BN=64, 1 barrier/step, fused z22
//                   epilogue); 512..543 t1 (BM=128,BN=32). 33.8KB LDS -> 2+ blk/CU
//   K3 gemm_y     : BM=64,BN=128, grid (8,64)=512 -> 2 blk/CU
//
// Z f16 cols: z00 0..31 | z10 32..63 | z11 64..95 | z20 96..127 | z21 128..159 | z22 160..191

typedef float f4 __attribute__((ext_vector_type(4)));
typedef _Float16 h8 __attribute__((ext_vector_type(8)));
typedef _Float16 h4 __attribute__((ext_vector_type(4)));
typedef unsigned int u32x4 __attribute__((ext_vector_type(4)));

// ws byte offsets
#define ZH_OFF  0u           // 4096*192 f16 = 1,572,864 B
#define TH_OFF  1572864u     // 4096*64 f16  =   524,288 B
#define OCH_OFF 2097152u     // 1024*96 f16  =   196,608 B
#define G2H_OFF 2293760u     // 1024*1024 f16 = 2,097,152 B (end 4,390,912)

__device__ __forceinline__ h8 splat8(unsigned int u) {
    _Float16 s = __builtin_bit_cast(_Float16, (unsigned short)(u & 0xffffu));
    return h8{ s, s, s, s, s, s, s, s };
}

// Integer-only broadcast-pair staging (the r9 miscompile fix): 16 halves
// (2 x uint4) -> 16 u32 broadcast pairs.
__device__ __forceinline__ void stage_bcast16(const _Float16* zsrc, unsigned int* dst) {
    u32x4 u0 = *(const u32x4*)zsrc;
    u32x4 u1 = *(const u32x4*)(zsrc + 8);
    #pragma unroll
    for (int k = 0; k < 4; ++k) {
        dst[2*k]       = (u0[k] & 0xffffu) * 0x00010001u;
        dst[2*k + 1]   = (u0[k] >> 16)     * 0x00010001u;
        dst[8 + 2*k]   = (u1[k] & 0xffffu) * 0x00010001u;
        dst[8 + 2*k+1] = (u1[k] >> 16)     * 0x00010001u;
    }
}

// ---------------- K1: prep + X-GEMM (r10 verbatim) ----------------
__global__ __launch_bounds__(256) void prep_gemmx(
    const float* __restrict__ X,
    const float* __restrict__ I0, const float* __restrict__ I1, const float* __restrict__ I2,
    const float* __restrict__ O0, const float* __restrict__ O1, const float* __restrict__ O2,
    const float* __restrict__ G0, const float* __restrict__ G2,
    _Float16* __restrict__ Och, _Float16* __restrict__ G2h, _Float16* __restrict__ Z)
{
    const int bx = blockIdx.x;
    const int t = threadIdx.x;
    if (bx >= 192) {
        if (bx < 1216) {           // G2 -> f16
            int i = ((bx - 192) * 256 + t) * 4;
            f4 v = *(const f4*)(G2 + i);
            h4 o = { (_Float16)v[0], (_Float16)v[1], (_Float16)v[2], (_Float16)v[3] };
            *(h4*)(G2h + i) = o;
        } else {                   // Och
            int idx = (bx - 1216) * 256 + t;
            int o = idx / 96, j = idx - o * 96;
            float v;
            if (j < 32) {
                v = 0.f;
                #pragma unroll
                for (int q = 0; q < 32; ++q) v += O0[o*32 + q] * G0[q*32 + j];
            } else if (j < 64) v = O1[o*32 + (j - 32)];
            else               v = O2[o*32 + (j - 64)];
            Och[idx] = (_Float16)v;
        }
        return;
    }
    __shared__ _Float16 As[64 * 64];
    __shared__ _Float16 Bs[64 * 64];
    const int work = (bx & 7) * 24 + (bx >> 3);       // XCD-chunked (192=8*24)
    const int m0 = (work / 3) * 64, n0 = (work % 3) * 64;
    const int wid = t >> 6, lane = t & 63;
    const int wr = wid >> 1, wc = wid & 1;
    const int lr = lane & 15, lg = lane >> 4;
    const int arow = t >> 2, aq = t & 3;

    const float* xbase = X + (size_t)(m0 + arow) * 1024 + aq * 16;
    const int wrow = n0 + arow;
    const float* wbase = (wrow < 32) ? I0 + (size_t)wrow * 1024
                       : (wrow < 96) ? I1 + (size_t)(wrow - 32) * 1024
                                     : I2 + (size_t)(wrow - 96) * 1024;
    wbase += aq * 16;
    const int sw0 = arow * 64 + (((aq * 2)     ^ (arow & 7)) << 3);
    const int sw1 = arow * 64 + (((aq * 2 + 1) ^ (arow & 7)) << 3);

    f4 xa[4], wa[4];
    #pragma unroll
    for (int q = 0; q < 4; ++q) { xa[q] = *(const f4*)(xbase + q*4); wa[q] = *(const f4*)(wbase + q*4); }

    f4 acc[2][2];
    #pragma unroll
    for (int mt = 0; mt < 2; ++mt)
        #pragma unroll
        for (int nt = 0; nt < 2; ++nt) acc[mt][nt] = f4{0.f,0.f,0.f,0.f};

    for (int s = 0; s < 16; ++s) {
        h8 ha0, ha1, hb0, hb1;
        #pragma unroll
        for (int j = 0; j < 4; ++j) {
            ha0[j] = (_Float16)xa[0][j]; ha0[4+j] = (_Float16)xa[1][j];
            ha1[j] = (_Float16)xa[2][j]; ha1[4+j] = (_Float16)xa[3][j];
            hb0[j] = (_Float16)wa[0][j]; hb0[4+j] = (_Float16)wa[1][j];
            hb1[j] = (_Float16)wa[2][j]; hb1[4+j] = (_Float16)wa[3][j];
        }
        *(h8*)&As[sw0] = ha0; *(h8*)&As[sw1] = ha1;
        *(h8*)&Bs[sw0] = hb0; *(h8*)&Bs[sw1] = hb1;
        __syncthreads();
        if (s < 15) {
            const float* xp = xbase + (s + 1) * 64;
            const float* wp = wbase + (s + 1) * 64;
            #pragma unroll
            for (int q = 0; q < 4; ++q) { xa[q] = *(const f4*)(xp + q*4); wa[q] = *(const f4*)(wp + q*4); }
        }
        #pragma unroll
        for (int ks = 0; ks < 2; ++ks) {
            h8 av[2], bv[2];
            #pragma unroll
            for (int mt = 0; mt < 2; ++mt) {
                int row = wr * 32 + mt * 16 + lr, gg = ks * 4 + lg;
                av[mt] = *(const h8*)&As[row * 64 + ((gg ^ (row & 7)) << 3)];
            }
            #pragma unroll
            for (int nt = 0; nt < 2; ++nt) {
                int row = wc * 32 + nt * 16 + lr, gg = ks * 4 + lg;
                bv[nt] = *(const h8*)&Bs[row * 64 + ((gg ^ (row & 7)) << 3)];
            }
            #pragma unroll
            for (int mt = 0; mt < 2; ++mt)
                #pragma unroll
                for (int nt = 0; nt < 2; ++nt)
                    acc[mt][nt] = __builtin_amdgcn_mfma_f32_16x16x32_f16(av[mt], bv[nt], acc[mt][nt], 0, 0, 0);
        }
        __syncthreads();
    }
    #pragma unroll
    for (int mt = 0; mt < 2; ++mt)
        #pragma unroll
        for (int nt = 0; nt < 2; ++nt)
            #pragma unroll
            for (int i = 0; i < 4; ++i)
                Z[(size_t)(m0 + wr*32 + mt*16 + lg*4 + i) * 192 + n0 + wc*32 + nt*16 + lr]
                    = (_Float16)acc[mt][nt][i];
}

// ---------------- K2: fused kron t2 + t1 ----------------
// t2 (bx<512): n0=(bx&15)*64, m0=(bx>>4)*128. BM=128,BN=64 (r9 body),
//   1 barrier/step double-buffered B, fused z22 epilogue.
// t1 (bx>=512): m0=(bx-512)*128, BN=32.
__global__ __launch_bounds__(256) void kron_fused(
    const _Float16* __restrict__ Z, const _Float16* __restrict__ G2h,
    const float* __restrict__ G1, _Float16* __restrict__ T)
{
    __shared__ __align__(16) unsigned char smem[33792];
    unsigned int* Zs1 = (unsigned int*)smem;               // [128][33]
    _Float16* Bs = (_Float16*)(smem + 16896);              // t2: [2][64][40]; t1: [2][32][40]
    const int bx = blockIdx.x;
    const int t = threadIdx.x;
    const int wid = t >> 6, lane = t & 63;
    const int lr = lane & 15, lg = lane >> 4;
    const bool is_t2 = bx < 512;
    const int m0 = is_t2 ? (bx >> 4) * 128 : (bx - 512) * 128;
    const int zcol = is_t2 ? 128 : 64;                     // z21 vs z11

    {   // outer z factor -> broadcast u32 pairs (integer-only)
        int row = t >> 1, c0 = (t & 1) * 16;
        stage_bcast16(Z + (size_t)(m0 + row) * 192 + zcol + c0, Zs1 + row * 33 + c0);
    }

    if (is_t2) {
        const int n0 = (bx & 15) * 64;
        const int wm0 = (wid >> 1) * 64, wn0 = (wid & 1) * 32;
        h8 a0v[4];
        #pragma unroll
        for (int mt = 0; mt < 4; ++mt)
            a0v[mt] = *(const h8*)(Z + (size_t)(m0 + wm0 + mt*16 + lr) * 192 + 96 + lg * 8);

        f4 acc[4][2];
        #pragma unroll
        for (int mt = 0; mt < 4; ++mt)
            #pragma unroll
            for (int nt = 0; nt < 2; ++nt) acc[mt][nt] = f4{0.f, 0.f, 0.f, 0.f};

        const int brow = t >> 2, bg = t & 3;
        const f4* gsrc = (const f4*)(G2h + (size_t)(n0 + brow) * 1024 + bg * 8);
        f4 breg = gsrc[0];
        int cur = 0;
        for (int s = 0; s < 32; ++s) {
            f4 bnext;
            if (s + 1 < 32) bnext = gsrc[(s + 1) * 4];
            *(f4*)&Bs[cur * 2560 + brow * 40 + bg * 8] = breg;
            __syncthreads();
            h8 bf0 = *(const h8*)&Bs[cur * 2560 + (wn0 + lr) * 40 + lg * 8];
            h8 bf1 = *(const h8*)&Bs[cur * 2560 + (wn0 + 16 + lr) * 40 + lg * 8];
            #pragma unroll
            for (int mt = 0; mt < 4; ++mt) {
                h8 z1b = splat8(Zs1[(wm0 + mt*16 + lr) * 33 + s]);
                h8 af = z1b * a0v[mt];
                acc[mt][0] = __builtin_amdgcn_mfma_f32_16x16x32_f16(af, bf0, acc[mt][0], 0, 0, 0);
                acc[mt][1] = __builtin_amdgcn_mfma_f32_16x16x32_f16(af, bf1, acc[mt][1], 0, 0, 0);
            }
            breg = bnext;
            cur ^= 1;
        }

        __syncthreads();
        float* Ms = (float*)smem;                          // [128][66]
        #pragma unroll
        for (int mt = 0; mt < 4; ++mt)
            #pragma unroll
            for (int nt = 0; nt < 2; ++nt)
                #pragma unroll
                for (int i = 0; i < 4; ++i)
                    Ms[(wm0 + mt*16 + lg*4 + i) * 66 + wn0 + nt*16 + lr] = acc[mt][nt][i];
        __syncthreads();
        {
            int row = t >> 1, rl = t & 1;
            const _Float16* z2p = Z + (size_t)(m0 + row) * 192 + 160;
            const float* mrow = Ms + row * 66 + rl * 32;
            float sum = 0.f;
            #pragma unroll
            for (int r2 = 0; r2 < 32; ++r2) sum += mrow[r2] * (float)z2p[r2];
            T[(size_t)(m0 + row) * 64 + 32 + (bx & 15) * 2 + rl] = (_Float16)sum;
        }
    } else {
        // ---- t1: kron(z11,z10) @ G1^T ----
        h8 a0v[2];
        #pragma unroll
        for (int mt = 0; mt < 2; ++mt)
            a0v[mt] = *(const h8*)(Z + (size_t)(m0 + wid*32 + mt*16 + lr) * 192 + 32 + lg * 8);

        const int brow = t >> 3, bq = (t & 7) * 4;
        const float* g1src = G1 + (size_t)brow * 1024 + bq;
        f4 bw = *(const f4*)g1src;
        {
            h4 bh = { (_Float16)bw[0], (_Float16)bw[1], (_Float16)bw[2], (_Float16)bw[3] };
            *(h4*)&Bs[brow * 40 + bq] = bh;
        }
        bw = *(const f4*)(g1src + 32);

        f4 acc[2][2];
        #pragma unroll
        for (int mt = 0; mt < 2; ++mt)
            #pragma unroll
            for (int nt = 0; nt < 2; ++nt) acc[mt][nt] = f4{0.f,0.f,0.f,0.f};
        __syncthreads();

        for (int s = 0; s < 32; ++s) {
            const int cur = s & 1;
            if (s < 31) {
                h4 bh = { (_Float16)bw[0], (_Float16)bw[1], (_Float16)bw[2], (_Float16)bw[3] };
                *(h4*)&Bs[(cur ^ 1) * 1280 + brow * 40 + bq] = bh;
            }
            if (s < 30) bw = *(const f4*)(g1src + (s + 2) * 32);
            h8 bf[2];
            #pragma unroll
            for (int nt = 0; nt < 2; ++nt)
                bf[nt] = *(const h8*)&Bs[cur * 1280 + (nt*16 + lr) * 40 + lg * 8];
            #pragma unroll
            for (int mt = 0; mt < 2; ++mt) {
                h8 z1b = splat8(Zs1[(wid*32 + mt*16 + lr) * 33 + s]);
                h8 af = z1b * a0v[mt];
                acc[mt][0] = __builtin_amdgcn_mfma_f32_16x16x32_f16(af, bf[0], acc[mt][0], 0, 0, 0);
                acc[mt][1] = __builtin_amdgcn_mfma_f32_16x16x32_f16(af, bf[1], acc[mt][1], 0, 0, 0);
            }
            __syncthreads();
        }
        #pragma unroll
        for (int mt = 0; mt < 2; ++mt)
            #pragma unroll
            for (int nt = 0; nt < 2; ++nt)
                #pragma unroll
                for (int i = 0; i < 4; ++i)
                    T[(size_t)(m0 + wid*32 + mt*16 + lg*4 + i) * 64 + nt*16 + lr]
                        = (_Float16)acc[mt][nt][i];
    }
}

// ---------------- K3: Y = const + [z00|T] @ Och^T  (BM=64, BN=128) ----------------
__global__ __launch_bounds__(256) void gemm_y_mfma(
    const _Float16* __restrict__ Z, const _Float16* __restrict__ T,
    const _Float16* __restrict__ Och, const float* __restrict__ cst,
    float* __restrict__ Y)
{
    __shared__ _Float16 As[64 * 104];
    __shared__ _Float16 Bs[128 * 104];
    const int t = threadIdx.x;
    const int n0 = blockIdx.x * 128, m0 = blockIdx.y * 64;
    {   // A: 64 rows x 96 = [z00 | T]; 4 threads/row, 24 halves each
        int row = t >> 2, seg = t & 3;
        const _Float16* zp = Z + (size_t)(m0 + row) * 192;
        const _Float16* tp = T + (size_t)(m0 + row) * 64;
        _Float16* dst = As + row * 104;
        if (seg == 0) {
            *(h8*)(dst)      = *(const h8*)(zp);
            *(h8*)(dst + 8)  = *(const h8*)(zp + 8);
            *(h8*)(dst + 16) = *(const h8*)(zp + 16);
        } else if (seg == 1) {
            *(h8*)(dst + 24) = *(const h8*)(zp + 24);
            *(h8*)(dst + 32) = *(const h8*)(tp);
            *(h8*)(dst + 40) = *(const h8*)(tp + 8);
        } else if (seg == 2) {
            *(h8*)(dst + 48) = *(const h8*)(tp + 16);
            *(h8*)(dst + 56) = *(const h8*)(tp + 24);
            *(h8*)(dst + 64) = *(const h8*)(tp + 32);
        } else {
            *(h8*)(dst + 72) = *(const h8*)(tp + 40);
            *(h8*)(dst + 80) = *(const h8*)(tp + 48);
            *(h8*)(dst + 88) = *(const h8*)(tp + 56);
        }
        // B: 128 rows x 96 Och
        int row2 = t >> 1, half = t & 1;
        const _Float16* src = Och + (size_t)(n0 + row2) * 96 + half * 48;
        _Float16* bdst = Bs + row2 * 104 + half * 48;
        #pragma unroll
        for (int q = 0; q < 6; ++q) *(h8*)(bdst + q * 8) = *(const h8*)(src + q * 8);
    }
    const int wid = t >> 6, lane = t & 63;
    const int wvr = wid >> 1, wvc = wid & 1;   // 2 m-waves x 2 n-waves
    const int lr = lane & 15, lg = lane >> 4;
    float bias[4];
    #pragma unroll
    for (int nt = 0; nt < 4; ++nt) bias[nt] = cst[n0 + wvc*64 + nt*16 + lr];
    __syncthreads();

    f4 acc[2][4];
    #pragma unroll
    for (int mt = 0; mt < 2; ++mt)
        #pragma unroll
        for (int nt = 0; nt < 4; ++nt) acc[mt][nt] = f4{0.f,0.f,0.f,0.f};

    #pragma unroll
    for (int ks = 0; ks < 3; ++ks) {
        h8 av[2], bv[4];
        #pragma unroll
        for (int mt = 0; mt < 2; ++mt)
            av[mt] = *(const h8*)&As[(wvr*32 + mt*16 + lr) * 104 + ks*32 + lg*8];
        #pragma unroll
        for (int nt = 0; nt < 4; ++nt)
            bv[nt] = *(const h8*)&Bs[(wvc*64 + nt*16 + lr) * 104 + ks*32 + lg*8];
        #pragma unroll
        for (int mt = 0; mt < 2; ++mt)
            #pragma unroll
            for (int nt = 0; nt < 4; ++nt)
                acc[mt][nt] = __builtin_amdgcn_mfma_f32_16x16x32_f16(av[mt], bv[nt], acc[mt][nt], 0, 0, 0);
    }
    #pragma unroll
    for (int mt = 0; mt < 2; ++mt)
        #pragma unroll
        for (int nt = 0; nt < 4; ++nt)
            #pragma unroll
            for (int i = 0; i < 4; ++i)
                Y[(size_t)(m0 + wvr*32 + mt*16 + lg*4 + i) * 1024 + n0 + wvc*64 + nt*16 + lr]
                    = acc[mt][nt][i] + bias[nt];
}

extern "C" void kernel_launch(void* const* d_in, const int* in_sizes, int n_in,
                              void* d_out, int out_size, void* d_ws, size_t ws_size,
                              hipStream_t stream) {
    const float* X   = (const float*)d_in[0];
    const float* cst = (const float*)d_in[1];
    const float* O0  = (const float*)d_in[2];
    const float* I0  = (const float*)d_in[3];
    const float* G0  = (const float*)d_in[4];
    const float* O1  = (const float*)d_in[5];
    const float* I1  = (const float*)d_in[6];
    const float* G1  = (const float*)d_in[7];
    const float* O2  = (const float*)d_in[8];
    const float* I2  = (const float*)d_in[9];
    const float* G2  = (const float*)d_in[10];
    unsigned char* ws = (unsigned char*)d_ws;
    _Float16* Zh  = (_Float16*)(ws + ZH_OFF);
    _Float16* Th  = (_Float16*)(ws + TH_OFF);
    _Float16* Oh  = (_Float16*)(ws + OCH_OFF);
    _Float16* G2h = (_Float16*)(ws + G2H_OFF);
    float* Y = (float*)d_out;

    prep_gemmx<<<1600, 256, 0, stream>>>(X, I0, I1, I2, O0, O1, O2, G0, G2, Oh, G2h, Zh);
    kron_fused<<<544, 256, 0, stream>>>(Zh, G2h, G1, Th);
    gemm_y_mfma<<<dim3(8, 64), 256, 0, stream>>>(Zh, Th, Oh, cst, Y);
}

// Round 13
// 39.827 us; speedup vs baseline: 4.8938x; 1.1952x over previous
//
#include <hip/hip_runtime.h>

// Fast Tucker-Taylor forward. Round 13: r12 with the K2 prologue fix
// (missing interval-2 register preload caused stale-B staging at i=1).
//   K1 prep_gemmx : X-GEMM 1 barrier/step, LDS dbuf, depth-2 prefetch.
//   K2 kron_fused : t2 with 2 K-slices per barrier interval (16 barriers).
//   K3 gemm_y     : unchanged (r11).
//
// Z f16 cols: z00 0..31 | z10 32..63 | z11 64..95 | z20 96..127 | z21 128..159 | z22 160..191

typedef float f4 __attribute__((ext_vector_type(4)));
typedef _Float16 h8 __attribute__((ext_vector_type(8)));
typedef _Float16 h4 __attribute__((ext_vector_type(4)));
typedef unsigned int u32x4 __attribute__((ext_vector_type(4)));

// ws byte offsets
#define ZH_OFF  0u           // 4096*192 f16 = 1,572,864 B
#define TH_OFF  1572864u     // 4096*64 f16  =   524,288 B
#define OCH_OFF 2097152u     // 1024*96 f16  =   196,608 B
#define G2H_OFF 2293760u     // 1024*1024 f16 = 2,097,152 B (end 4,390,912)

__device__ __forceinline__ h8 splat8(unsigned int u) {
    _Float16 s = __builtin_bit_cast(_Float16, (unsigned short)(u & 0xffffu));
    return h8{ s, s, s, s, s, s, s, s };
}

// Integer-only broadcast-pair staging (r9 miscompile fix): 16 halves
// (2 x uint4) -> 16 u32 broadcast pairs.
__device__ __forceinline__ void stage_bcast16(const _Float16* zsrc, unsigned int* dst) {
    u32x4 u0 = *(const u32x4*)zsrc;
    u32x4 u1 = *(const u32x4*)(zsrc + 8);
    #pragma unroll
    for (int k = 0; k < 4; ++k) {
        dst[2*k]       = (u0[k] & 0xffffu) * 0x00010001u;
        dst[2*k + 1]   = (u0[k] >> 16)     * 0x00010001u;
        dst[8 + 2*k]   = (u1[k] & 0xffffu) * 0x00010001u;
        dst[8 + 2*k+1] = (u1[k] >> 16)     * 0x00010001u;
    }
}

// ---------------- K1: prep + X-GEMM ----------------
__global__ __launch_bounds__(256) void prep_gemmx(
    const float* __restrict__ X,
    const float* __restrict__ I0, const float* __restrict__ I1, const float* __restrict__ I2,
    const float* __restrict__ O0, const float* __restrict__ O1, const float* __restrict__ O2,
    const float* __restrict__ G0, const float* __restrict__ G2,
    _Float16* __restrict__ Och, _Float16* __restrict__ G2h, _Float16* __restrict__ Z)
{
    const int bx = blockIdx.x;
    const int t = threadIdx.x;
    if (bx >= 192) {
        if (bx < 1216) {           // G2 -> f16
            int i = ((bx - 192) * 256 + t) * 4;
            f4 v = *(const f4*)(G2 + i);
            h4 o = { (_Float16)v[0], (_Float16)v[1], (_Float16)v[2], (_Float16)v[3] };
            *(h4*)(G2h + i) = o;
        } else {                   // Och
            int idx = (bx - 1216) * 256 + t;
            int o = idx / 96, j = idx - o * 96;
            float v;
            if (j < 32) {
                v = 0.f;
                #pragma unroll
                for (int q = 0; q < 32; ++q) v += O0[o*32 + q] * G0[q*32 + j];
            } else if (j < 64) v = O1[o*32 + (j - 32)];
            else               v = O2[o*32 + (j - 64)];
            Och[idx] = (_Float16)v;
        }
        return;
    }
    // ---- X-GEMM: Z = f16( X @ Wcat^T ); LDS dbuf, 1 barrier/step, depth-2 ----
    __shared__ _Float16 As[2][64 * 64];
    __shared__ _Float16 Bs[2][64 * 64];
    const int work = (bx & 7) * 24 + (bx >> 3);       // XCD-chunked (192=8*24)
    const int m0 = (work / 3) * 64, n0 = (work % 3) * 64;
    const int wid = t >> 6, lane = t & 63;
    const int wr = wid >> 1, wc = wid & 1;
    const int lr = lane & 15, lg = lane >> 4;
    const int arow = t >> 2, aq = t & 3;

    const float* xbase = X + (size_t)(m0 + arow) * 1024 + aq * 16;
    const int wrow = n0 + arow;
    const float* wbase = (wrow < 32) ? I0 + (size_t)wrow * 1024
                       : (wrow < 96) ? I1 + (size_t)(wrow - 32) * 1024
                                     : I2 + (size_t)(wrow - 96) * 1024;
    wbase += aq * 16;
    const int sw0 = arow * 64 + (((aq * 2)     ^ (arow & 7)) << 3);
    const int sw1 = arow * 64 + (((aq * 2 + 1) ^ (arow & 7)) << 3);

    f4 xa[2][4], wa[2][4];
    #define LOADX(set, step) { \
        const float* xp = xbase + (step) * 64; \
        const float* wp = wbase + (step) * 64; \
        _Pragma("unroll") \
        for (int q = 0; q < 4; ++q) { xa[set][q] = *(const f4*)(xp + q*4); wa[set][q] = *(const f4*)(wp + q*4); } }
    #define STAGE(set, buf) { \
        h8 ha0, ha1, hb0, hb1; \
        _Pragma("unroll") \
        for (int j = 0; j < 4; ++j) { \
            ha0[j] = (_Float16)xa[set][0][j]; ha0[4+j] = (_Float16)xa[set][1][j]; \
            ha1[j] = (_Float16)xa[set][2][j]; ha1[4+j] = (_Float16)xa[set][3][j]; \
            hb0[j] = (_Float16)wa[set][0][j]; hb0[4+j] = (_Float16)wa[set][1][j]; \
            hb1[j] = (_Float16)wa[set][2][j]; hb1[4+j] = (_Float16)wa[set][3][j]; \
        } \
        *(h8*)&As[buf][sw0] = ha0; *(h8*)&As[buf][sw1] = ha1; \
        *(h8*)&Bs[buf][sw0] = hb0; *(h8*)&Bs[buf][sw1] = hb1; }

    LOADX(0, 0); LOADX(1, 1);
    STAGE(0, 0);
    LOADX(0, 2);

    f4 acc[2][2];
    #pragma unroll
    for (int mt = 0; mt < 2; ++mt)
        #pragma unroll
        for (int nt = 0; nt < 2; ++nt) acc[mt][nt] = f4{0.f,0.f,0.f,0.f};

    #pragma unroll
    for (int s = 0; s < 16; ++s) {
        const int cur = s & 1;
        __syncthreads();
        if (s < 15) STAGE((s + 1) & 1, cur ^ 1);
        if (s < 13) LOADX((s + 1) & 1, s + 3);
        #pragma unroll
        for (int ks = 0; ks < 2; ++ks) {
            h8 av[2], bv[2];
            #pragma unroll
            for (int mt = 0; mt < 2; ++mt) {
                int row = wr * 32 + mt * 16 + lr, gg = ks * 4 + lg;
                av[mt] = *(const h8*)&As[cur][row * 64 + ((gg ^ (row & 7)) << 3)];
            }
            #pragma unroll
            for (int nt = 0; nt < 2; ++nt) {
                int row = wc * 32 + nt * 16 + lr, gg = ks * 4 + lg;
                bv[nt] = *(const h8*)&Bs[cur][row * 64 + ((gg ^ (row & 7)) << 3)];
            }
            #pragma unroll
            for (int mt = 0; mt < 2; ++mt)
                #pragma unroll
                for (int nt = 0; nt < 2; ++nt)
                    acc[mt][nt] = __builtin_amdgcn_mfma_f32_16x16x32_f16(av[mt], bv[nt], acc[mt][nt], 0, 0, 0);
        }
    }
    #undef LOADX
    #undef STAGE
    #pragma unroll
    for (int mt = 0; mt < 2; ++mt)
        #pragma unroll
        for (int nt = 0; nt < 2; ++nt)
            #pragma unroll
            for (int i = 0; i < 4; ++i)
                Z[(size_t)(m0 + wr*32 + mt*16 + lg*4 + i) * 192 + n0 + wc*32 + nt*16 + lr]
                    = (_Float16)acc[mt][nt][i];
}

// ---------------- K2: fused kron t2 + t1 ----------------
// t2 (bx<512): n0=(bx&15)*64, m0=(bx>>4)*128. BM=128,BN=64; 2 K-slices per
//   barrier interval (16 barriers), LDS dbuf, 2-interval prefetch; fused z22.
// t1 (bx>=512): m0=(bx-512)*128, BN=32 (r11 verbatim).
__global__ __launch_bounds__(256) void kron_fused(
    const _Float16* __restrict__ Z, const _Float16* __restrict__ G2h,
    const float* __restrict__ G1, _Float16* __restrict__ T)
{
    __shared__ __align__(16) unsigned char smem[37376];
    unsigned int* Zs1 = (unsigned int*)smem;               // [128][33]
    _Float16* Bs = (_Float16*)(smem + 16896);              // t2: [2][2][64][40]; t1: [2][32][40]
    const int bx = blockIdx.x;
    const int t = threadIdx.x;
    const int wid = t >> 6, lane = t & 63;
    const int lr = lane & 15, lg = lane >> 4;
    const bool is_t2 = bx < 512;
    const int m0 = is_t2 ? (bx >> 4) * 128 : (bx - 512) * 128;
    const int zcol = is_t2 ? 128 : 64;                     // z21 vs z11

    {   // outer z factor -> broadcast u32 pairs (integer-only)
        int row = t >> 1, c0 = (t & 1) * 16;
        stage_bcast16(Z + (size_t)(m0 + row) * 192 + zcol + c0, Zs1 + row * 33 + c0);
    }

    if (is_t2) {
        const int n0 = (bx & 15) * 64;
        const int wm0 = (wid >> 1) * 64, wn0 = (wid & 1) * 32;
        h8 a0v[4];
        #pragma unroll
        for (int mt = 0; mt < 4; ++mt)
            a0v[mt] = *(const h8*)(Z + (size_t)(m0 + wm0 + mt*16 + lr) * 192 + 96 + lg * 8);

        f4 acc[4][2];
        #pragma unroll
        for (int mt = 0; mt < 4; ++mt)
            #pragma unroll
            for (int nt = 0; nt < 2; ++nt) acc[mt][nt] = f4{0.f, 0.f, 0.f, 0.f};

        const int brow = t >> 2, bg = t & 3;
        const f4* gsrc = (const f4*)(G2h + (size_t)(n0 + brow) * 1024 + bg * 8);
        // interval i covers slices 2i, 2i+1 -> gsrc[8i], gsrc[8i+4]
        f4 brA[2], brB[2];
        brA[0] = gsrc[0];  brB[0] = gsrc[4];     // interval 0
        {   // stage interval 0 -> buf 0
            *(f4*)&Bs[0 * 5120 + 0 * 2560 + brow * 40 + bg * 8] = brA[0];
            *(f4*)&Bs[0 * 5120 + 1 * 2560 + brow * 40 + bg * 8] = brB[0];
        }
        brA[1] = gsrc[8];  brB[1] = gsrc[12];    // interval 1
        brA[0] = gsrc[16]; brB[0] = gsrc[20];    // interval 2 (the r12 fix)

        #pragma unroll
        for (int i = 0; i < 16; ++i) {
            const int cur = i & 1;
            __syncthreads();
            if (i < 15) {
                const int set = (i + 1) & 1;
                *(f4*)&Bs[(cur ^ 1) * 5120 + 0 * 2560 + brow * 40 + bg * 8] = brA[set];
                *(f4*)&Bs[(cur ^ 1) * 5120 + 1 * 2560 + brow * 40 + bg * 8] = brB[set];
            }
            if (i < 13) {
                const int set = (i + 1) & 1;
                brA[set] = gsrc[(i + 3) * 8];
                brB[set] = gsrc[(i + 3) * 8 + 4];
            }
            #pragma unroll
            for (int q = 0; q < 2; ++q) {
                h8 bf0 = *(const h8*)&Bs[cur * 5120 + q * 2560 + (wn0 + lr) * 40 + lg * 8];
                h8 bf1 = *(const h8*)&Bs[cur * 5120 + q * 2560 + (wn0 + 16 + lr) * 40 + lg * 8];
                #pragma unroll
                for (int mt = 0; mt < 4; ++mt) {
                    h8 z1b = splat8(Zs1[(wm0 + mt*16 + lr) * 33 + 2*i + q]);
                    h8 af = z1b * a0v[mt];
                    acc[mt][0] = __builtin_amdgcn_mfma_f32_16x16x32_f16(af, bf0, acc[mt][0], 0, 0, 0);
                    acc[mt][1] = __builtin_amdgcn_mfma_f32_16x16x32_f16(af, bf1, acc[mt][1], 0, 0, 0);
                }
            }
        }

        __syncthreads();
        float* Ms = (float*)smem;                          // [128][66]
        #pragma unroll
        for (int mt = 0; mt < 4; ++mt)
            #pragma unroll
            for (int nt = 0; nt < 2; ++nt)
                #pragma unroll
                for (int i = 0; i < 4; ++i)
                    Ms[(wm0 + mt*16 + lg*4 + i) * 66 + wn0 + nt*16 + lr] = acc[mt][nt][i];
        __syncthreads();
        {
            int row = t >> 1, rl = t & 1;
            const _Float16* z2p = Z + (size_t)(m0 + row) * 192 + 160;
            const float* mrow = Ms + row * 66 + rl * 32;
            float sum = 0.f;
            #pragma unroll
            for (int r2 = 0; r2 < 32; ++r2) sum += mrow[r2] * (float)z2p[r2];
            T[(size_t)(m0 + row) * 64 + 32 + (bx & 15) * 2 + rl] = (_Float16)sum;
        }
    } else {
        // ---- t1: kron(z11,z10) @ G1^T (r11 verbatim) ----
        h8 a0v[2];
        #pragma unroll
        for (int mt = 0; mt < 2; ++mt)
            a0v[mt] = *(const h8*)(Z + (size_t)(m0 + wid*32 + mt*16 + lr) * 192 + 32 + lg * 8);

        const int brow = t >> 3, bq = (t & 7) * 4;
        const float* g1src = G1 + (size_t)brow * 1024 + bq;
        f4 bw = *(const f4*)g1src;
        {
            h4 bh = { (_Float16)bw[0], (_Float16)bw[1], (_Float16)bw[2], (_Float16)bw[3] };
            *(h4*)&Bs[brow * 40 + bq] = bh;
        }
        bw = *(const f4*)(g1src + 32);

        f4 acc[2][2];
        #pragma unroll
        for (int mt = 0; mt < 2; ++mt)
            #pragma unroll
            for (int nt = 0; nt < 2; ++nt) acc[mt][nt] = f4{0.f,0.f,0.f,0.f};
        __syncthreads();

        for (int s = 0; s < 32; ++s) {
            const int cur = s & 1;
            if (s < 31) {
                h4 bh = { (_Float16)bw[0], (_Float16)bw[1], (_Float16)bw[2], (_Float16)bw[3] };
                *(h4*)&Bs[(cur ^ 1) * 1280 + brow * 40 + bq] = bh;
            }
            if (s < 30) bw = *(const f4*)(g1src + (s + 2) * 32);
            h8 bf[2];
            #pragma unroll
            for (int nt = 0; nt < 2; ++nt)
                bf[nt] = *(const h8*)&Bs[cur * 1280 + (nt*16 + lr) * 40 + lg * 8];
            #pragma unroll
            for (int mt = 0; mt < 2; ++mt) {
                h8 z1b = splat8(Zs1[(wid*32 + mt*16 + lr) * 33 + s]);
                h8 af = z1b * a0v[mt];
                acc[mt][0] = __builtin_amdgcn_mfma_f32_16x16x32_f16(af, bf[0], acc[mt][0], 0, 0, 0);
                acc[mt][1] = __builtin_amdgcn_mfma_f32_16x16x32_f16(af, bf[1], acc[mt][1], 0, 0, 0);
            }
            __syncthreads();
        }
        #pragma unroll
        for (int mt = 0; mt < 2; ++mt)
            #pragma unroll
            for (int nt = 0; nt < 2; ++nt)
                #pragma unroll
                for (int i = 0; i < 4; ++i)
                    T[(size_t)(m0 + wid*32 + mt*16 + lg*4 + i) * 64 + nt*16 + lr]
                        = (_Float16)acc[mt][nt][i];
    }
}

// ---------------- K3: Y = const + [z00|T] @ Och^T  (BM=64, BN=128; r11) ----------------
__global__ __launch_bounds__(256) void gemm_y_mfma(
    const _Float16* __restrict__ Z, const _Float16* __restrict__ T,
    const _Float16* __restrict__ Och, const float* __restrict__ cst,
    float* __restrict__ Y)
{
    __shared__ _Float16 As[64 * 104];
    __shared__ _Float16 Bs[128 * 104];
    const int t = threadIdx.x;
    const int n0 = blockIdx.x * 128, m0 = blockIdx.y * 64;
    {   // A: 64 rows x 96 = [z00 | T]; 4 threads/row, 24 halves each
        int row = t >> 2, seg = t & 3;
        const _Float16* zp = Z + (size_t)(m0 + row) * 192;
        const _Float16* tp = T + (size_t)(m0 + row) * 64;
        _Float16* dst = As + row * 104;
        if (seg == 0) {
            *(h8*)(dst)      = *(const h8*)(zp);
            *(h8*)(dst + 8)  = *(const h8*)(zp + 8);
            *(h8*)(dst + 16) = *(const h8*)(zp + 16);
        } else if (seg == 1) {
            *(h8*)(dst + 24) = *(const h8*)(zp + 24);
            *(h8*)(dst + 32) = *(const h8*)(tp);
            *(h8*)(dst + 40) = *(const h8*)(tp + 8);
        } else if (seg == 2) {
            *(h8*)(dst + 48) = *(const h8*)(tp + 16);
            *(h8*)(dst + 56) = *(const h8*)(tp + 24);
            *(h8*)(dst + 64) = *(const h8*)(tp + 32);
        } else {
            *(h8*)(dst + 72) = *(const h8*)(tp + 40);
            *(h8*)(dst + 80) = *(const h8*)(tp + 48);
            *(h8*)(dst + 88) = *(const h8*)(tp + 56);
        }
        // B: 128 rows x 96 Och
        int row2 = t >> 1, half = t & 1;
        const _Float16* src = Och + (size_t)(n0 + row2) * 96 + half * 48;
        _Float16* bdst = Bs + row2 * 104 + half * 48;
        #pragma unroll
        for (int q = 0; q < 6; ++q) *(h8*)(bdst + q * 8) = *(const h8*)(src + q * 8);
    }
    const int wid = t >> 6, lane = t & 63;
    const int wvr = wid >> 1, wvc = wid & 1;   // 2 m-waves x 2 n-waves
    const int lr = lane & 15, lg = lane >> 4;
    float bias[4];
    #pragma unroll
    for (int nt = 0; nt < 4; ++nt) bias[nt] = cst[n0 + wvc*64 + nt*16 + lr];
    __syncthreads();

    f4 acc[2][4];
    #pragma unroll
    for (int mt = 0; mt < 2; ++mt)
        #pragma unroll
        for (int nt = 0; nt < 4; ++nt) acc[mt][nt] = f4{0.f,0.f,0.f,0.f};

    #pragma unroll
    for (int ks = 0; ks < 3; ++ks) {
        h8 av[2], bv[4];
        #pragma unroll
        for (int mt = 0; mt < 2; ++mt)
            av[mt] = *(const h8*)&As[(wvr*32 + mt*16 + lr) * 104 + ks*32 + lg*8];
        #pragma unroll
        for (int nt = 0; nt < 4; ++nt)
            bv[nt] = *(const h8*)&Bs[(wvc*64 + nt*16 + lr) * 104 + ks*32 + lg*8];
        #pragma unroll
        for (int mt = 0; mt < 2; ++mt)
            #pragma unroll
            for (int nt = 0; nt < 4; ++nt)
                acc[mt][nt] = __builtin_amdgcn_mfma_f32_16x16x32_f16(av[mt], bv[nt], acc[mt][nt], 0, 0, 0);
    }
    #pragma unroll
    for (int mt = 0; mt < 2; ++mt)
        #pragma unroll
        for (int nt = 0; nt < 4; ++nt)
            #pragma unroll
            for (int i = 0; i < 4; ++i)
                Y[(size_t)(m0 + wvr*32 + mt*16 + lg*4 + i) * 1024 + n0 + wvc*64 + nt*16 + lr]
                    = acc[mt][nt][i] + bias[nt];
}

extern "C" void kernel_launch(void* const* d_in, const int* in_sizes, int n_in,
                              void* d_out, int out_size, void* d_ws, size_t ws_size,
                              hipStream_t stream) {
    const float* X   = (const float*)d_in[0];
    const float* cst = (const float*)d_in[1];
    const float* O0  = (const float*)d_in[2];
    const float* I0  = (const float*)d_in[3];
    const float* G0  = (const float*)d_in[4];
    const float* O1  = (const float*)d_in[5];
    const float* I1  = (const float*)d_in[6];
    const float* G1  = (const float*)d_in[7];
    const float* O2  = (const float*)d_in[8];
    const float* I2  = (const float*)d_in[9];
    const float* G2  = (const float*)d_in[10];
    unsigned char* ws = (unsigned char*)d_ws;
    _Float16* Zh  = (_Float16*)(ws + ZH_OFF);
    _Float16* Th  = (_Float16*)(ws + TH_OFF);
    _Float16* Oh  = (_Float16*)(ws + OCH_OFF);
    _Float16* G2h = (_Float16*)(ws + G2H_OFF);
    float* Y = (float*)d_out;

    prep_gemmx<<<1600, 256, 0, stream>>>(X, I0, I1, I2, O0, O1, O2, G0, G2, Oh, G2h, Zh);
    kron_fused<<<544, 256, 0, stream>>>(Zh, G2h, G1, Th);
    gemm_y_mfma<<<dim3(8, 64), 256, 0, stream>>>(Zh, Th, Oh, cst, Y);
}